// Round 1
// baseline (9285.908 us; speedup 1.0000x reference)
//
#include <hip/hip_runtime.h>
#include <hip/hip_bf16.h>

#define NN 50000
#define DEG 16
#define NEDGE (NN*DEG)

__device__ __forceinline__ float sigmoidf_(float x){ return 1.f/(1.f + __expf(-x)); }
__device__ __forceinline__ float tanh_fast(float x){
  float e = __expf(-2.f*fabsf(x));
  float r = (1.f - e)/(1.f + e);
  return copysignf(r, x);
}

// out[n][j0+jj] = A@W^T (+ A2@W2^T) + bias (+bias2), optional relu.
// A, A2: [n][128]; W: [J][wstride] (uses cols kh..); out stride = ostride.
// Block: 256 thr, 64 rows x 128 cols (j0 = blockIdx.y*128).
__global__ __launch_bounds__(256,2) void k_gemm(
    const float* __restrict__ A, const float* __restrict__ A2,
    const float* __restrict__ W, const float* __restrict__ W2,
    int wstride, int w2stride,
    const float* __restrict__ bias, const float* __restrict__ bias2,
    float* __restrict__ out, int ostride, int dorelu, int n)
{
  __shared__ float Ast[128*68];   // Ast[k][nl]
  __shared__ float Ws[64*132];    // Ws[kk][j]
  const int t  = threadIdx.x;
  const int g  = t & 15, ng = t >> 4;
  const int nr = ng * 4;
  const int n0 = blockIdx.x * 64;
  const int j0 = blockIdx.y * 128;

  float acc[4][8];
#pragma unroll
  for (int i=0;i<4;i++)
#pragma unroll
    for (int u=0;u<8;u++) acc[i][u]=0.f;

  auto stageA = [&](const float* __restrict__ Ap){
#pragma unroll
    for (int i=0;i<8;i++){
      int idx4 = t + 256*i;
      int nl = idx4 >> 5, k4 = (idx4 & 31)*4;
      float4 v = {0.f,0.f,0.f,0.f};
      if (n0+nl < n) v = *(const float4*)(Ap + (size_t)(n0+nl)*128 + k4);
      Ast[(k4+0)*68+nl]=v.x; Ast[(k4+1)*68+nl]=v.y;
      Ast[(k4+2)*68+nl]=v.z; Ast[(k4+3)*68+nl]=v.w;
    }
  };
  auto stageW = [&](const float* __restrict__ Wp, int wsd, int kh){
#pragma unroll
    for (int i=0;i<8;i++){
      int idx4 = t + 256*i;
      int j = idx4 >> 4, k4 = (idx4 & 15)*4;
      float4 v = *(const float4*)(Wp + (size_t)(j0+j)*wsd + kh + k4);
      Ws[(k4+0)*132+j]=v.x; Ws[(k4+1)*132+j]=v.y;
      Ws[(k4+2)*132+j]=v.z; Ws[(k4+3)*132+j]=v.w;
    }
  };
  auto mmacc = [&](int kh){
    for (int kk=0; kk<64; kk++){
      float4 a  = *(const float4*)&Ast[(kh+kk)*68 + nr];
      float4 w0 = *(const float4*)&Ws[kk*132 + g*4];
      float4 w1 = *(const float4*)&Ws[kk*132 + 64 + g*4];
      const float av[4] = {a.x,a.y,a.z,a.w};
#pragma unroll
      for (int i=0;i<4;i++){
        acc[i][0]+=av[i]*w0.x; acc[i][1]+=av[i]*w0.y; acc[i][2]+=av[i]*w0.z; acc[i][3]+=av[i]*w0.w;
        acc[i][4]+=av[i]*w1.x; acc[i][5]+=av[i]*w1.y; acc[i][6]+=av[i]*w1.z; acc[i][7]+=av[i]*w1.w;
      }
    }
  };

  stageA(A);
  stageW(W, wstride, 0);
  __syncthreads();
  mmacc(0);
  __syncthreads();
  stageW(W, wstride, 64);
  __syncthreads();
  mmacc(64);
  if (A2){
    __syncthreads();
    stageA(A2);
    stageW(W2, w2stride, 0);
    __syncthreads();
    mmacc(0);
    __syncthreads();
    stageW(W2, w2stride, 64);
    __syncthreads();
    mmacc(64);
  }

  float bv[8];
#pragma unroll
  for (int u=0;u<8;u++){
    int jc = j0 + g*4 + (u&3) + (u>>2)*64;
    float b = bias ? bias[jc] : 0.f;
    if (bias2) b += bias2[jc];
    bv[u] = b;
  }
#pragma unroll
  for (int i=0;i<4;i++){
    int nn2 = n0 + nr + i;
    if (nn2 < n){
      float4 o0, o1;
      o0.x=acc[i][0]+bv[0]; o0.y=acc[i][1]+bv[1]; o0.z=acc[i][2]+bv[2]; o0.w=acc[i][3]+bv[3];
      o1.x=acc[i][4]+bv[4]; o1.y=acc[i][5]+bv[5]; o1.z=acc[i][6]+bv[6]; o1.w=acc[i][7]+bv[7];
      if (dorelu){
        o0.x=fmaxf(o0.x,0.f); o0.y=fmaxf(o0.y,0.f); o0.z=fmaxf(o0.z,0.f); o0.w=fmaxf(o0.w,0.f);
        o1.x=fmaxf(o1.x,0.f); o1.y=fmaxf(o1.y,0.f); o1.z=fmaxf(o1.z,0.f); o1.w=fmaxf(o1.w,0.f);
      }
      *(float4*)(out + (size_t)nn2*ostride + j0 + g*4)      = o0;
      *(float4*)(out + (size_t)nn2*ostride + j0 + 64 + g*4) = o1;
    }
  }
}

// Persistent LSTM over 16 steps for 64 nodes/block.
// G: [N][512] precomputed x@Wih.T + bih + bhh. gates = G[src[n*16+t]] + h@Whh.T.
__global__ __launch_bounds__(256,2) void k_lstm(
    const float* __restrict__ G, const int* __restrict__ src,
    const float* __restrict__ Whh, float* __restrict__ agg, int n)
{
  __shared__ float Ast[128*68];   // h^T: Ast[k][nl]
  __shared__ float Ws[64*132];    // Whh tile [kk][j]
  __shared__ int   srcs[64*16];
  const int t  = threadIdx.x;
  const int g  = t & 15, ng = t >> 4;
  const int nr = ng*4;
  const int n0 = blockIdx.x * 64;

  for (int i = t; i < 1024; i += 256){
    int nl = i >> 4, tt = i & 15;
    srcs[i] = (n0+nl < n) ? src[(size_t)(n0+nl)*16 + tt] : 0;
  }
  for (int i = t; i < 128*68; i += 256) Ast[i] = 0.f;
  float c[4][8];
#pragma unroll
  for (int i=0;i<4;i++)
#pragma unroll
    for (int u=0;u<8;u++) c[i][u]=0.f;
  __syncthreads();

  auto stageW = [&](int gt, int kh){
#pragma unroll
    for (int i=0;i<8;i++){
      int idx4 = t + 256*i;
      int j = idx4 >> 4, k4 = (idx4 & 15)*4;
      float4 v = *(const float4*)(Whh + (size_t)(gt*128 + j)*128 + kh + k4);
      Ws[(k4+0)*132+j]=v.x; Ws[(k4+1)*132+j]=v.y;
      Ws[(k4+2)*132+j]=v.z; Ws[(k4+3)*132+j]=v.w;
    }
  };

  for (int step=0; step<16; step++){
    float gates[4][4][8];
#pragma unroll
    for (int gt=0; gt<4; gt++){
      // init acc from gathered G rows
#pragma unroll
      for (int i=0;i<4;i++){
        int gi = srcs[(nr+i)*16 + step];
        const float* Gr = G + (size_t)gi*512 + gt*128;
        float4 v0 = *(const float4*)(Gr + g*4);
        float4 v1 = *(const float4*)(Gr + 64 + g*4);
        gates[gt][i][0]=v0.x; gates[gt][i][1]=v0.y; gates[gt][i][2]=v0.z; gates[gt][i][3]=v0.w;
        gates[gt][i][4]=v1.x; gates[gt][i][5]=v1.y; gates[gt][i][6]=v1.z; gates[gt][i][7]=v1.w;
      }
      for (int kh=0; kh<128; kh+=64){
        __syncthreads();          // prior Ws readers / prior-step h-writes done
        stageW(gt, kh);
        __syncthreads();
        for (int kk=0; kk<64; kk++){
          float4 a  = *(const float4*)&Ast[(kh+kk)*68 + nr];
          float4 w0 = *(const float4*)&Ws[kk*132 + g*4];
          float4 w1 = *(const float4*)&Ws[kk*132 + 64 + g*4];
          const float av[4]={a.x,a.y,a.z,a.w};
#pragma unroll
          for (int i=0;i<4;i++){
            gates[gt][i][0]+=av[i]*w0.x; gates[gt][i][1]+=av[i]*w0.y;
            gates[gt][i][2]+=av[i]*w0.z; gates[gt][i][3]+=av[i]*w0.w;
            gates[gt][i][4]+=av[i]*w1.x; gates[gt][i][5]+=av[i]*w1.y;
            gates[gt][i][6]+=av[i]*w1.z; gates[gt][i][7]+=av[i]*w1.w;
          }
        }
      }
    }
    __syncthreads();   // all Ast reads done before overwriting with h_t
#pragma unroll
    for (int i=0;i<4;i++)
#pragma unroll
      for (int u=0;u<8;u++){
        float ip=gates[0][i][u], fp=gates[1][i][u], gp=gates[2][i][u], op=gates[3][i][u];
        float cn = sigmoidf_(fp)*c[i][u] + sigmoidf_(ip)*tanh_fast(gp);
        c[i][u]=cn;
        float h = sigmoidf_(op)*tanh_fast(cn);
        int col = g*4 + (u&3) + (u>>2)*64;
        Ast[col*68 + nr + i] = h;
      }
    // next iteration's first __syncthreads() (or the final one) orders these writes
  }
  __syncthreads();
#pragma unroll
  for (int i=0;i<4;i++){
    int nn2 = n0 + nr + i;
    if (nn2 < n){
      float4 o0, o1;
      o0.x = Ast[(g*4+0)*68 + nr+i]; o0.y = Ast[(g*4+1)*68 + nr+i];
      o0.z = Ast[(g*4+2)*68 + nr+i]; o0.w = Ast[(g*4+3)*68 + nr+i];
      o1.x = Ast[(64+g*4+0)*68 + nr+i]; o1.y = Ast[(64+g*4+1)*68 + nr+i];
      o1.z = Ast[(64+g*4+2)*68 + nr+i]; o1.w = Ast[(64+g*4+3)*68 + nr+i];
      *(float4*)(agg + (size_t)nn2*128 + g*4)      = o0;
      *(float4*)(agg + (size_t)nn2*128 + 64 + g*4) = o1;
    }
  }
}

// Edge MLP: one block per destination node (16 edges, sorted by dst).
// out1 = relu(Hs[src] + Hd[dst] + ea@W1e^T + b1); e2 = relu(out1@W2^T + b2); out = e2@W3^T + b3.
__global__ __launch_bounds__(256,2) void k_edge(
    const float* __restrict__ Hs, const float* __restrict__ Hd,
    const float* __restrict__ ea, const int* __restrict__ src,
    const float* __restrict__ W1, const float* __restrict__ b1,
    const float* __restrict__ W2, const float* __restrict__ b2,
    const float* __restrict__ W3, const float* __restrict__ b3,
    float* __restrict__ out)
{
  __shared__ float W2s[64*132];    // [j][k]
  __shared__ float W1eT[16*130];   // [k][c]
  __shared__ float out1s[16*132];  // [e][c]
  __shared__ float e2s[16*68];     // [e][j]
  __shared__ float W3s[2*64];
  __shared__ float b1s[128];
  __shared__ float b2s[64];
  __shared__ float b3s[2];
  __shared__ float eas[16*17];
  __shared__ int   srcs[16];

  const int t = threadIdx.x;
  const int nblk = blockIdx.x;

#pragma unroll
  for (int i=0;i<8;i++){
    int idx4 = t + 256*i;              // 2048 float4 of W2
    int j = idx4 >> 5, k4 = (idx4 & 31)*4;
    *(float4*)&W2s[j*132 + k4] = *(const float4*)(W2 + (size_t)j*128 + k4);
  }
  for (int i = t; i < 2048; i += 256){
    int j = i >> 4, k = i & 15;
    W1eT[k*130 + j] = W1[(size_t)j*272 + 256 + k];
  }
  if (t < 128) b1s[t] = b1[t];
  if (t < 64)  b2s[t] = b2[t];
  if (t < 128) W3s[t] = W3[t];
  if (t < 2)   b3s[t] = b3[t];
  if (t < 16)  srcs[t] = src[(size_t)nblk*16 + t];
  { int e = t >> 4, k = t & 15; eas[e*17+k] = ea[(size_t)nblk*256 + t]; }
  __syncthreads();

  // phase 1: out1  (thread: e = t>>4 (16), cl = t&15; 8 cols each: c = cl + 16u)
  {
    const int e = t >> 4, cl = t & 15;
    const float* HsRow = Hs + (size_t)srcs[e]*128;
    const float* HdRow = Hd + (size_t)nblk*128;
    float a1[8];
#pragma unroll
    for (int u=0;u<8;u++){
      int cc = cl + 16*u;
      a1[u] = b1s[cc] + HsRow[cc] + HdRow[cc];
    }
#pragma unroll
    for (int k=0;k<16;k++){
      float av = eas[e*17+k];
#pragma unroll
      for (int u=0;u<8;u++) a1[u] += av * W1eT[k*130 + cl + 16*u];
    }
#pragma unroll
    for (int u=0;u<8;u++){
      int cc = cl + 16*u;
      out1s[e*132 + cc] = fmaxf(a1[u], 0.f);
    }
  }
  __syncthreads();

  // phase 2: e2 (thread: j = t&63, edge group eg = t>>6 handles 4 edges)
  {
    const int j = t & 63, eg = t >> 6;
    float a2[4];
#pragma unroll
    for (int i=0;i<4;i++) a2[i] = b2s[j];
    for (int k4=0;k4<32;k4++){
      float4 w = *(const float4*)&W2s[j*132 + 4*k4];
#pragma unroll
      for (int i=0;i<4;i++){
        float4 o1 = *(const float4*)&out1s[(eg*4+i)*132 + 4*k4];
        a2[i] += o1.x*w.x + o1.y*w.y + o1.z*w.z + o1.w*w.w;
      }
    }
#pragma unroll
    for (int i=0;i<4;i++) e2s[(eg*4+i)*68 + j] = fmaxf(a2[i], 0.f);
  }
  __syncthreads();

  // phase 3: out (32 threads: e = t>>1, o = t&1)
  if (t < 32){
    int e = t >> 1, o = t & 1;
    float v = b3s[o];
    for (int k=0;k<64;k++) v += e2s[e*68 + k] * W3s[o*64 + k];
    out[((size_t)nblk*16 + e)*2 + o] = v;
  }
}

extern "C" void kernel_launch(void* const* d_in, const int* in_sizes, int n_in,
                              void* d_out, int out_size, void* d_ws, size_t ws_size,
                              hipStream_t stream) {
  const float* x    = (const float*)d_in[0];
  const int*   eidx = (const int*)  d_in[1];
  const float* eatt = (const float*)d_in[2];
  const float* Wih  = (const float*)d_in[3];
  const float* Whh  = (const float*)d_in[4];
  const float* bih  = (const float*)d_in[5];
  const float* bhh  = (const float*)d_in[6];
  const float* WlL  = (const float*)d_in[7];
  const float* blL  = (const float*)d_in[8];
  const float* WrL  = (const float*)d_in[9];
  const float* W1   = (const float*)d_in[10];
  const float* b1   = (const float*)d_in[11];
  const float* W2   = (const float*)d_in[12];
  const float* b2   = (const float*)d_in[13];
  const float* W3   = (const float*)d_in[14];
  const float* b3   = (const float*)d_in[15];
  const int*   src  = eidx;             // edge_index[0]

  float* ws  = (float*)d_ws;
  float* G   = ws;                          // N*512
  float* agg = G   + (size_t)NN*512;        // N*128
  float* hA  = agg + (size_t)NN*128;        // N*128
  float* hB  = hA  + (size_t)NN*128;        // N*128
  float* Hs  = G;                           // reuse (post-LSTM)
  float* Hd  = G + (size_t)NN*128;

  dim3 blk(256);
  const int nb = (NN + 63)/64;

  const float* hin = x;
  float* houts[3] = {hA, hB, hA};
  for (int l = 0; l < 3; l++){
    k_gemm<<<dim3(nb,4),blk,0,stream>>>(hin, nullptr,
        Wih + (size_t)l*512*128, nullptr, 128, 0,
        bih + (size_t)l*512, bhh + (size_t)l*512,
        G, 512, 0, NN);
    k_lstm<<<dim3(nb),blk,0,stream>>>(G, src, Whh + (size_t)l*512*128, agg, NN);
    k_gemm<<<dim3(nb,1),blk,0,stream>>>(agg, hin,
        WlL + (size_t)l*128*128, WrL + (size_t)l*128*128, 128, 128,
        blL + (size_t)l*128, nullptr,
        houts[l], 128, 1, NN);
    hin = houts[l];
  }
  // hin == hA (final node features)
  k_gemm<<<dim3(nb,1),blk,0,stream>>>(hin, nullptr, W1,       nullptr, 272, 0,
                                      nullptr, nullptr, Hs, 128, 0, NN);
  k_gemm<<<dim3(nb,1),blk,0,stream>>>(hin, nullptr, W1 + 128, nullptr, 272, 0,
                                      nullptr, nullptr, Hd, 128, 0, NN);
  k_edge<<<dim3(NN),blk,0,stream>>>(Hs, Hd, eatt, src, W1, b1, W2, b2, W3, b3,
                                    (float*)d_out);
}

// Round 2
// 2847.137 us; speedup vs baseline: 3.2615x; 3.2615x over previous
//
#include <hip/hip_runtime.h>
#include <hip/hip_bf16.h>

#define NN 50000
#define DEG 16

typedef __attribute__((ext_vector_type(8))) short bfrag;   // 8 x bf16 bits
typedef __attribute__((ext_vector_type(4))) float f32x4;

__device__ __forceinline__ float bf2f(unsigned int u){ return __uint_as_float(u<<16); }
__device__ __forceinline__ unsigned short f2bf(float x){
  unsigned int u = __float_as_uint(x);
  unsigned int r = (u + 0x7fffu + ((u>>16)&1u)) >> 16;
  return (unsigned short)r;
}
__device__ __forceinline__ float fast_rcp(float x){ return __builtin_amdgcn_rcpf(x); }
__device__ __forceinline__ float sigmoidf_(float x){ return fast_rcp(1.f + __expf(-x)); }
__device__ __forceinline__ float tanh_fast(float x){
  float e = __expf(-2.f*fabsf(x));
  float r = (1.f - e)*fast_rcp(1.f + e);
  return copysignf(r, x);
}

// out[n][j0+jj] = A@W^T (+ A2@W2^T) + bias (+bias2), optional relu, optional bf16 out.
__global__ __launch_bounds__(256,2) void k_gemm(
    const float* __restrict__ A, const float* __restrict__ A2,
    const float* __restrict__ W, const float* __restrict__ W2,
    int wstride, int w2stride,
    const float* __restrict__ bias, const float* __restrict__ bias2,
    void* __restrict__ out, int ostride, int dorelu, int out_bf16, int n)
{
  __shared__ float Ast[128*68];   // Ast[k][nl]
  __shared__ float Ws[64*132];    // Ws[kk][j]
  const int t  = threadIdx.x;
  const int g  = t & 15, ng = t >> 4;
  const int nr = ng * 4;
  const int n0 = blockIdx.x * 64;
  const int j0 = blockIdx.y * 128;

  float acc[4][8];
#pragma unroll
  for (int i=0;i<4;i++)
#pragma unroll
    for (int u=0;u<8;u++) acc[i][u]=0.f;

  auto stageA = [&](const float* __restrict__ Ap){
#pragma unroll
    for (int i=0;i<8;i++){
      int idx4 = t + 256*i;
      int nl = idx4 >> 5, k4 = (idx4 & 31)*4;
      float4 v = {0.f,0.f,0.f,0.f};
      if (n0+nl < n) v = *(const float4*)(Ap + (size_t)(n0+nl)*128 + k4);
      Ast[(k4+0)*68+nl]=v.x; Ast[(k4+1)*68+nl]=v.y;
      Ast[(k4+2)*68+nl]=v.z; Ast[(k4+3)*68+nl]=v.w;
    }
  };
  auto stageW = [&](const float* __restrict__ Wp, int wsd, int kh){
#pragma unroll
    for (int i=0;i<8;i++){
      int idx4 = t + 256*i;
      int j = idx4 >> 4, k4 = (idx4 & 15)*4;
      float4 v = *(const float4*)(Wp + (size_t)(j0+j)*wsd + kh + k4);
      Ws[(k4+0)*132+j]=v.x; Ws[(k4+1)*132+j]=v.y;
      Ws[(k4+2)*132+j]=v.z; Ws[(k4+3)*132+j]=v.w;
    }
  };
  auto mmacc = [&](int kh){
    for (int kk=0; kk<64; kk++){
      float4 a  = *(const float4*)&Ast[(kh+kk)*68 + nr];
      float4 w0 = *(const float4*)&Ws[kk*132 + g*4];
      float4 w1 = *(const float4*)&Ws[kk*132 + 64 + g*4];
      const float av[4] = {a.x,a.y,a.z,a.w};
#pragma unroll
      for (int i=0;i<4;i++){
        acc[i][0]+=av[i]*w0.x; acc[i][1]+=av[i]*w0.y; acc[i][2]+=av[i]*w0.z; acc[i][3]+=av[i]*w0.w;
        acc[i][4]+=av[i]*w1.x; acc[i][5]+=av[i]*w1.y; acc[i][6]+=av[i]*w1.z; acc[i][7]+=av[i]*w1.w;
      }
    }
  };

  stageA(A);
  stageW(W, wstride, 0);
  __syncthreads();
  mmacc(0);
  __syncthreads();
  stageW(W, wstride, 64);
  __syncthreads();
  mmacc(64);
  if (A2){
    __syncthreads();
    stageA(A2);
    stageW(W2, w2stride, 0);
    __syncthreads();
    mmacc(0);
    __syncthreads();
    stageW(W2, w2stride, 64);
    __syncthreads();
    mmacc(64);
  }

  float bv[8];
#pragma unroll
  for (int u=0;u<8;u++){
    int jc = j0 + g*4 + (u&3) + (u>>2)*64;
    float b = bias ? bias[jc] : 0.f;
    if (bias2) b += bias2[jc];
    bv[u] = b;
  }
#pragma unroll
  for (int i=0;i<4;i++){
    int nn2 = n0 + nr + i;
    if (nn2 < n){
      float4 o0, o1;
      o0.x=acc[i][0]+bv[0]; o0.y=acc[i][1]+bv[1]; o0.z=acc[i][2]+bv[2]; o0.w=acc[i][3]+bv[3];
      o1.x=acc[i][4]+bv[4]; o1.y=acc[i][5]+bv[5]; o1.z=acc[i][6]+bv[6]; o1.w=acc[i][7]+bv[7];
      if (dorelu){
        o0.x=fmaxf(o0.x,0.f); o0.y=fmaxf(o0.y,0.f); o0.z=fmaxf(o0.z,0.f); o0.w=fmaxf(o0.w,0.f);
        o1.x=fmaxf(o1.x,0.f); o1.y=fmaxf(o1.y,0.f); o1.z=fmaxf(o1.z,0.f); o1.w=fmaxf(o1.w,0.f);
      }
      if (out_bf16){
        unsigned short* ob = (unsigned short*)out;
        uint2 p0, p1;
        p0.x = (unsigned int)f2bf(o0.x) | ((unsigned int)f2bf(o0.y)<<16);
        p0.y = (unsigned int)f2bf(o0.z) | ((unsigned int)f2bf(o0.w)<<16);
        p1.x = (unsigned int)f2bf(o1.x) | ((unsigned int)f2bf(o1.y)<<16);
        p1.y = (unsigned int)f2bf(o1.z) | ((unsigned int)f2bf(o1.w)<<16);
        *(uint2*)(ob + (size_t)nn2*ostride + j0 + g*4)      = p0;
        *(uint2*)(ob + (size_t)nn2*ostride + j0 + 64 + g*4) = p1;
      } else {
        float* of = (float*)out;
        *(float4*)(of + (size_t)nn2*ostride + j0 + g*4)      = o0;
        *(float4*)(of + (size_t)nn2*ostride + j0 + 64 + g*4) = o1;
      }
    }
  }
}

__global__ void k_cvt(const float* __restrict__ in, unsigned short* __restrict__ out, int n){
  int i = blockIdx.x*256 + threadIdx.x;
  if (i < n) out[i] = f2bf(in[i]);
}

// MFMA LSTM, transposed: D[gate][node] = Whh_slice . h^T, gates += G[src].
// Block = 256 thr (4 waves), 64 nodes. Wave w owns hidden units [32w,32w+32)
// across all 4 gate types. Whh A-frags persistent in registers. h in LDS bf16,
// XOR-swizzled (row&7)<<4. G gathered per-lane (8B loads, C-layout aligned).
__global__ __launch_bounds__(256,1) void k_lstm2(
    const unsigned short* __restrict__ G,    // [n][512] bf16 (x@Wih^T + bih + bhh)
    const int* __restrict__ src,             // [n*16]
    const unsigned short* __restrict__ Whhb, // [512][128] bf16
    float* __restrict__ agg, int n)
{
  __shared__ unsigned short hs[64*128];      // 16 KB, row=node (256B), swizzled
  __shared__ int srcs[64*17];                // padded stride 17
  const int t  = threadIdx.x;
  const int l  = t & 63;
  const int w  = t >> 6;
  const int ln = l & 15;
  const int q  = l >> 4;
  const int n0 = blockIdx.x * 64;

  for (int i = t; i < 1024; i += 256){
    int nl = i >> 4, st = i & 15;
    srcs[nl*17 + st] = (n0+nl < n) ? src[(size_t)(n0+nl)*16 + st] : 0;
  }
  for (int i = t; i < 64*128; i += 256) hs[i] = 0;

  // A-frags: lane provides A[m=ln][k=ks*32+8q+e] with m -> gate T*128+w*32+u*16+ln
  bfrag A[4][2][4];
#pragma unroll
  for (int T=0;T<4;T++)
#pragma unroll
    for (int u=0;u<2;u++)
#pragma unroll
      for (int ks=0;ks<4;ks++){
        int gate = T*128 + w*32 + u*16 + ln;
        A[T][u][ks] = *(const bfrag*)(Whhb + (size_t)gate*128 + ks*32 + q*8);
      }

  float c[2][4][4];
#pragma unroll
  for (int u=0;u<2;u++)
#pragma unroll
    for (int nt=0;nt<4;nt++)
#pragma unroll
      for (int r=0;r<4;r++) c[u][nt][r]=0.f;

  __syncthreads();

  for (int step=0; step<16; step++){
    // gather gate-inits: lane needs G[src[node]][gate..gate+3], node=nt*16+ln
    uint2 gvv[4][4][2];   // [nt][T][u]
#pragma unroll
    for (int nt=0;nt<4;nt++){
      int node = nt*16 + ln;
      int sidx = srcs[node*17 + step];
      const unsigned short* Grow = G + (size_t)sidx*512;
#pragma unroll
      for (int T=0;T<4;T++)
#pragma unroll
        for (int u=0;u<2;u++)
          gvv[nt][T][u] = *(const uint2*)(Grow + T*128 + w*32 + u*16 + q*4);
    }
    // B-frags: lane provides B[k=ks*32+8q+e][n=ln] = h[node][k]
    bfrag B[4][4];        // [nt][ks]
    if (step > 0){
#pragma unroll
      for (int nt=0;nt<4;nt++)
#pragma unroll
        for (int ks=0;ks<4;ks++){
          int node = nt*16 + ln;
          int kb = (ks*32 + q*8)*2;
          B[nt][ks] = *(const bfrag*)((const char*)hs + node*256 + (kb ^ ((node&7)<<4)));
        }
    }
    f32x4 acc[4][2][4];   // [T][u][nt]
#pragma unroll
    for (int T=0;T<4;T++)
#pragma unroll
      for (int u=0;u<2;u++)
#pragma unroll
        for (int nt=0;nt<4;nt++){
          uint2 g2 = gvv[nt][T][u];
          f32x4 a;
          a[0]=bf2f(g2.x & 0xffffu); a[1]=bf2f(g2.x >> 16);
          a[2]=bf2f(g2.y & 0xffffu); a[3]=bf2f(g2.y >> 16);
          acc[T][u][nt]=a;
        }
    if (step > 0){
#pragma unroll
      for (int T=0;T<4;T++)
#pragma unroll
        for (int u=0;u<2;u++)
#pragma unroll
          for (int nt=0;nt<4;nt++)
#pragma unroll
            for (int ks=0;ks<4;ks++)
              acc[T][u][nt] = __builtin_amdgcn_mfma_f32_16x16x32_bf16(
                  A[T][u][ks], B[nt][ks], acc[T][u][nt], 0, 0, 0);
    }
    __syncthreads();   // all h reads done before overwrite
#pragma unroll
    for (int u=0;u<2;u++)
#pragma unroll
      for (int nt=0;nt<4;nt++){
        int node = nt*16 + ln;
        unsigned int lo=0, hi=0;
#pragma unroll
        for (int r=0;r<4;r++){
          float iv = acc[0][u][nt][r];
          float fv = acc[1][u][nt][r];
          float gv = acc[2][u][nt][r];
          float ov = acc[3][u][nt][r];
          float cn = sigmoidf_(fv)*c[u][nt][r] + sigmoidf_(iv)*tanh_fast(gv);
          c[u][nt][r] = cn;
          float h = sigmoidf_(ov)*tanh_fast(cn);
          unsigned int hb = f2bf(h);
          if (r<2) lo |= hb << (16*r); else hi |= hb << (16*(r-2));
        }
        int kb = (w*32 + u*16 + q*4)*2;
        uint2* p = (uint2*)((char*)hs + node*256 + (kb ^ ((node&7)<<4)));
        uint2 pv; pv.x = lo; pv.y = hi;
        *p = pv;
      }
    __syncthreads();   // h writes visible for next step
  }

#pragma unroll
  for (int u=0;u<2;u++)
#pragma unroll
    for (int nt=0;nt<4;nt++){
      int node = nt*16 + ln;
      if (n0+node < n){
        int kb = (w*32 + u*16 + q*4)*2;
        const uint2* p = (const uint2*)((const char*)hs + node*256 + (kb ^ ((node&7)<<4)));
        uint2 v = *p;
        float4 o;
        o.x=bf2f(v.x & 0xffffu); o.y=bf2f(v.x >> 16);
        o.z=bf2f(v.y & 0xffffu); o.w=bf2f(v.y >> 16);
        *(float4*)(agg + (size_t)(n0+node)*128 + w*32 + u*16 + q*4) = o;
      }
    }
}

// Edge MLP: one block per destination node (16 edges, sorted by dst).
__global__ __launch_bounds__(256,2) void k_edge(
    const float* __restrict__ Hs, const float* __restrict__ Hd,
    const float* __restrict__ ea, const int* __restrict__ src,
    const float* __restrict__ W1, const float* __restrict__ b1,
    const float* __restrict__ W2, const float* __restrict__ b2,
    const float* __restrict__ W3, const float* __restrict__ b3,
    float* __restrict__ out)
{
  __shared__ float W2s[64*132];
  __shared__ float W1eT[16*130];
  __shared__ float out1s[16*132];
  __shared__ float e2s[16*68];
  __shared__ float W3s[2*64];
  __shared__ float b1s[128];
  __shared__ float b2s[64];
  __shared__ float b3s[2];
  __shared__ float eas[16*17];
  __shared__ int   srcs[16];

  const int t = threadIdx.x;
  const int nblk = blockIdx.x;

#pragma unroll
  for (int i=0;i<8;i++){
    int idx4 = t + 256*i;
    int j = idx4 >> 5, k4 = (idx4 & 31)*4;
    *(float4*)&W2s[j*132 + k4] = *(const float4*)(W2 + (size_t)j*128 + k4);
  }
  for (int i = t; i < 2048; i += 256){
    int j = i >> 4, k = i & 15;
    W1eT[k*130 + j] = W1[(size_t)j*272 + 256 + k];
  }
  if (t < 128) b1s[t] = b1[t];
  if (t < 64)  b2s[t] = b2[t];
  if (t < 128) W3s[t] = W3[t];
  if (t < 2)   b3s[t] = b3[t];
  if (t < 16)  srcs[t] = src[(size_t)nblk*16 + t];
  { int e = t >> 4, k = t & 15; eas[e*17+k] = ea[(size_t)nblk*256 + t]; }
  __syncthreads();

  {
    const int e = t >> 4, cl = t & 15;
    const float* HsRow = Hs + (size_t)srcs[e]*128;
    const float* HdRow = Hd + (size_t)nblk*128;
    float a1[8];
#pragma unroll
    for (int u=0;u<8;u++){
      int cc = cl + 16*u;
      a1[u] = b1s[cc] + HsRow[cc] + HdRow[cc];
    }
#pragma unroll
    for (int k=0;k<16;k++){
      float av = eas[e*17+k];
#pragma unroll
      for (int u=0;u<8;u++) a1[u] += av * W1eT[k*130 + cl + 16*u];
    }
#pragma unroll
    for (int u=0;u<8;u++){
      int cc = cl + 16*u;
      out1s[e*132 + cc] = fmaxf(a1[u], 0.f);
    }
  }
  __syncthreads();

  {
    const int j = t & 63, eg = t >> 6;
    float a2[4];
#pragma unroll
    for (int i=0;i<4;i++) a2[i] = b2s[j];
    for (int k4=0;k4<32;k4++){
      float4 wv = *(const float4*)&W2s[j*132 + 4*k4];
#pragma unroll
      for (int i=0;i<4;i++){
        float4 o1 = *(const float4*)&out1s[(eg*4+i)*132 + 4*k4];
        a2[i] += o1.x*wv.x + o1.y*wv.y + o1.z*wv.z + o1.w*wv.w;
      }
    }
#pragma unroll
    for (int i=0;i<4;i++) e2s[(eg*4+i)*68 + j] = fmaxf(a2[i], 0.f);
  }
  __syncthreads();

  if (t < 32){
    int e = t >> 1, o = t & 1;
    float v = b3s[o];
    for (int k=0;k<64;k++) v += e2s[e*68 + k] * W3s[o*64 + k];
    out[((size_t)nblk*16 + e)*2 + o] = v;
  }
}

extern "C" void kernel_launch(void* const* d_in, const int* in_sizes, int n_in,
                              void* d_out, int out_size, void* d_ws, size_t ws_size,
                              hipStream_t stream) {
  const float* x    = (const float*)d_in[0];
  const int*   eidx = (const int*)  d_in[1];
  const float* eatt = (const float*)d_in[2];
  const float* Wih  = (const float*)d_in[3];
  const float* Whh  = (const float*)d_in[4];
  const float* bih  = (const float*)d_in[5];
  const float* bhh  = (const float*)d_in[6];
  const float* WlL  = (const float*)d_in[7];
  const float* blL  = (const float*)d_in[8];
  const float* WrL  = (const float*)d_in[9];
  const float* W1   = (const float*)d_in[10];
  const float* b1   = (const float*)d_in[11];
  const float* W2   = (const float*)d_in[12];
  const float* b2   = (const float*)d_in[13];
  const float* W3   = (const float*)d_in[14];
  const float* b3   = (const float*)d_in[15];
  const int*   src  = eidx;

  float* ws = (float*)d_ws;
  unsigned short* Gb = (unsigned short*)ws;              // NN*512 bf16
  float* agg = ws + (size_t)NN*256;                      // NN*128 f32
  float* hA  = agg + (size_t)NN*128;
  float* hB  = hA  + (size_t)NN*128;
  unsigned short* Whhb = (unsigned short*)(hB + (size_t)NN*128);  // 3*512*128 bf16
  float* Hs = (float*)Gb;                                 // reuse after LSTMs
  float* Hd = Hs + (size_t)NN*128;

  dim3 blk(256);
  const int nb = (NN + 63)/64;

  k_cvt<<<(3*512*128 + 255)/256, blk, 0, stream>>>(Whh, Whhb, 3*512*128);

  const float* hin = x;
  float* houts[3] = {hA, hB, hA};
  for (int l = 0; l < 3; l++){
    k_gemm<<<dim3(nb,4),blk,0,stream>>>(hin, nullptr,
        Wih + (size_t)l*512*128, nullptr, 128, 0,
        bih + (size_t)l*512, bhh + (size_t)l*512,
        (void*)Gb, 512, 0, 1, NN);
    k_lstm2<<<dim3(nb),blk,0,stream>>>(Gb, src, Whhb + (size_t)l*512*128, agg, NN);
    k_gemm<<<dim3(nb,1),blk,0,stream>>>(agg, hin,
        WlL + (size_t)l*128*128, WrL + (size_t)l*128*128, 128, 128,
        blL + (size_t)l*128, nullptr,
        (void*)houts[l], 128, 1, 0, NN);
    hin = houts[l];
  }
  k_gemm<<<dim3(nb,1),blk,0,stream>>>(hin, nullptr, W1,       nullptr, 272, 0,
                                      nullptr, nullptr, (void*)Hs, 128, 0, 0, NN);
  k_gemm<<<dim3(nb,1),blk,0,stream>>>(hin, nullptr, W1 + 128, nullptr, 272, 0,
                                      nullptr, nullptr, (void*)Hd, 128, 0, 0, NN);
  k_edge<<<dim3(NN),blk,0,stream>>>(Hs, Hd, eatt, src, W1, b1, W2, b2, W3, b3,
                                    (float*)d_out);
}

// Round 3
// 2170.766 us; speedup vs baseline: 4.2777x; 1.3116x over previous
//
#include <hip/hip_runtime.h>
#include <hip/hip_bf16.h>

#define NN 50000
#define DEG 16

typedef __attribute__((ext_vector_type(8))) short bfrag;   // 8 x bf16 bits (16B)
typedef __attribute__((ext_vector_type(4))) float f32x4;

__device__ __forceinline__ float bf2f(unsigned int u){ return __uint_as_float(u<<16); }
__device__ __forceinline__ unsigned short f2bf(float x){
  unsigned int u = __float_as_uint(x);
  unsigned int r = (u + 0x7fffu + ((u>>16)&1u)) >> 16;
  return (unsigned short)r;
}
__device__ __forceinline__ float fast_rcp(float x){ return __builtin_amdgcn_rcpf(x); }
__device__ __forceinline__ float sigmoidf_(float x){ return fast_rcp(1.f + __expf(-x)); }
__device__ __forceinline__ float tanh_fast(float x){
  float e = __expf(-2.f*fabsf(x));
  float r = (1.f - e)*fast_rcp(1.f + e);
  return copysignf(r, x);
}

// swizzle: 16B-slot XOR, decorrelates row bit3 so write-side (q*4+r) rows also spread
#define SWZ(row) (((((row) ^ ((row)>>3)) & 7)) << 4)

__global__ void k_cvt(const float* __restrict__ in, unsigned short* __restrict__ out, int n){
  int i = blockIdx.x*256 + threadIdx.x;
  if (i < n) out[i] = f2bf(in[i]);
}

__global__ void k_cvt2(const float* __restrict__ in, unsigned short* __restrict__ out,
                       int stride, int off, int cols, int total){
  int i = blockIdx.x*256 + threadIdx.x;
  if (i < total){
    int r = i / cols, c = i - r*cols;
    out[i] = f2bf(in[(size_t)r*stride + off + c]);
  }
}

// edge weights prep: W2 hi/lo [64][128], W1e hi/lo [128][16], W3p [16][64] (zero-padded rows 2..15)
__global__ void k_prep_edge(const float* __restrict__ W1, const float* __restrict__ W2,
                            const float* __restrict__ W3,
                            unsigned short* __restrict__ W1eh, unsigned short* __restrict__ W1el,
                            unsigned short* __restrict__ W2h, unsigned short* __restrict__ W2l,
                            unsigned short* __restrict__ W3p)
{
  int i = blockIdx.x*256 + threadIdx.x;
  if (i < 8192){
    float v = W2[i];
    unsigned short hi = f2bf(v);
    W2h[i] = hi; W2l[i] = f2bf(v - bf2f(hi));
  } else if (i < 10240){
    int k = i - 8192; int j = k >> 4, kk = k & 15;
    float v = W1[(size_t)j*272 + 256 + kk];
    unsigned short hi = f2bf(v);
    W1eh[k] = hi; W1el[k] = f2bf(v - bf2f(hi));
  } else if (i < 11264){
    int k = i - 10240; int nr = k >> 6, c = k & 63;
    W3p[k] = f2bf(nr < 2 ? W3[nr*64 + c] : 0.f);
  }
}

// bf16 MFMA gemm: out[row][j] = A@W^T (+A2@W2^T) + bias (+bias2). K=128 fixed.
// A: [n][128] bf16 row-major; W: [J][128] bf16 row-major. Block: 64 rows x 128 cols,
// 4 waves each own a 32-col slice. Direct global->reg fragment loads (no LDS).
__global__ __launch_bounds__(256,4) void k_bgemm(
    const unsigned short* __restrict__ Ab, const unsigned short* __restrict__ A2b,
    const unsigned short* __restrict__ Wb, const unsigned short* __restrict__ W2b,
    const float* __restrict__ bias, const float* __restrict__ bias2,
    float* __restrict__ outF, unsigned short* __restrict__ outB,
    int ostride, int dorelu, int n)
{
  const int t  = threadIdx.x;
  const int w  = t >> 6;
  const int l  = t & 63;
  const int ln = l & 15, q = l >> 4;
  const int n0 = blockIdx.x*64;
  const int j0 = blockIdx.y*128 + w*32;

  int nodeM[4];
#pragma unroll
  for (int mt=0;mt<4;mt++){ int nd = n0 + mt*16 + ln; nodeM[mt] = nd < n ? nd : n-1; }

  f32x4 acc[4][2];
#pragma unroll
  for (int mt=0;mt<4;mt++)
#pragma unroll
    for (int nt=0;nt<2;nt++) acc[mt][nt] = (f32x4){0.f,0.f,0.f,0.f};

  auto pass = [&](const unsigned short* __restrict__ Ap, const unsigned short* __restrict__ Wp){
#pragma unroll
    for (int ks=0;ks<4;ks++){
      bfrag Af[4], Bf[2];
#pragma unroll
      for (int mt=0;mt<4;mt++)
        Af[mt] = *(const bfrag*)(Ap + (size_t)nodeM[mt]*128 + ks*32 + q*8);
#pragma unroll
      for (int nt=0;nt<2;nt++)
        Bf[nt] = *(const bfrag*)(Wp + (size_t)(j0 + nt*16 + ln)*128 + ks*32 + q*8);
#pragma unroll
      for (int mt=0;mt<4;mt++)
#pragma unroll
        for (int nt=0;nt<2;nt++)
          acc[mt][nt] = __builtin_amdgcn_mfma_f32_16x16x32_bf16(Af[mt], Bf[nt], acc[mt][nt], 0,0,0);
    }
  };
  pass(Ab, Wb);
  if (A2b) pass(A2b, W2b);

#pragma unroll
  for (int nt=0;nt<2;nt++){
    int j = j0 + nt*16 + ln;
    float bv = bias ? bias[j] : 0.f;
    if (bias2) bv += bias2[j];
#pragma unroll
    for (int mt=0;mt<4;mt++)
#pragma unroll
      for (int r=0;r<4;r++){
        int row = n0 + mt*16 + q*4 + r;
        if (row < n){
          float v = acc[mt][nt][r] + bv;
          if (dorelu) v = fmaxf(v, 0.f);
          if (outF) outF[(size_t)row*ostride + j] = v;
          if (outB) outB[(size_t)row*ostride + j] = f2bf(v);
        }
      }
  }
}

// MFMA LSTM (transposed): unchanged from R2 except agg output is bf16 (lossless).
__global__ __launch_bounds__(256,1) void k_lstm2(
    const unsigned short* __restrict__ G,    // [n][512] bf16
    const int* __restrict__ src,             // [n*16]
    const unsigned short* __restrict__ Whhb, // [512][128] bf16
    unsigned short* __restrict__ aggb, int n)
{
  __shared__ unsigned short hs[64*128];
  __shared__ int srcs[64*17];
  const int t  = threadIdx.x;
  const int l  = t & 63;
  const int w  = t >> 6;
  const int ln = l & 15;
  const int q  = l >> 4;
  const int n0 = blockIdx.x * 64;

  for (int i = t; i < 1024; i += 256){
    int nl = i >> 4, st = i & 15;
    srcs[nl*17 + st] = (n0+nl < n) ? src[(size_t)(n0+nl)*16 + st] : 0;
  }
  for (int i = t; i < 64*128; i += 256) hs[i] = 0;

  bfrag A[4][2][4];
#pragma unroll
  for (int T=0;T<4;T++)
#pragma unroll
    for (int u=0;u<2;u++)
#pragma unroll
      for (int ks=0;ks<4;ks++){
        int gate = T*128 + w*32 + u*16 + ln;
        A[T][u][ks] = *(const bfrag*)(Whhb + (size_t)gate*128 + ks*32 + q*8);
      }

  float c[2][4][4];
#pragma unroll
  for (int u=0;u<2;u++)
#pragma unroll
    for (int nt=0;nt<4;nt++)
#pragma unroll
      for (int r=0;r<4;r++) c[u][nt][r]=0.f;

  __syncthreads();

  for (int step=0; step<16; step++){
    uint2 gvv[4][4][2];
#pragma unroll
    for (int nt=0;nt<4;nt++){
      int node = nt*16 + ln;
      int sidx = srcs[node*17 + step];
      const unsigned short* Grow = G + (size_t)sidx*512;
#pragma unroll
      for (int T=0;T<4;T++)
#pragma unroll
        for (int u=0;u<2;u++)
          gvv[nt][T][u] = *(const uint2*)(Grow + T*128 + w*32 + u*16 + q*4);
    }
    bfrag B[4][4];
    if (step > 0){
#pragma unroll
      for (int nt=0;nt<4;nt++)
#pragma unroll
        for (int ks=0;ks<4;ks++){
          int node = nt*16 + ln;
          int kb = (ks*32 + q*8)*2;
          B[nt][ks] = *(const bfrag*)((const char*)hs + node*256 + (kb ^ ((node&7)<<4)));
        }
    }
    f32x4 acc[4][2][4];
#pragma unroll
    for (int T=0;T<4;T++)
#pragma unroll
      for (int u=0;u<2;u++)
#pragma unroll
        for (int nt=0;nt<4;nt++){
          uint2 g2 = gvv[nt][T][u];
          f32x4 a;
          a[0]=bf2f(g2.x & 0xffffu); a[1]=bf2f(g2.x >> 16);
          a[2]=bf2f(g2.y & 0xffffu); a[3]=bf2f(g2.y >> 16);
          acc[T][u][nt]=a;
        }
    if (step > 0){
#pragma unroll
      for (int T=0;T<4;T++)
#pragma unroll
        for (int u=0;u<2;u++)
#pragma unroll
          for (int nt=0;nt<4;nt++)
#pragma unroll
            for (int ks=0;ks<4;ks++)
              acc[T][u][nt] = __builtin_amdgcn_mfma_f32_16x16x32_bf16(
                  A[T][u][ks], B[nt][ks], acc[T][u][nt], 0, 0, 0);
    }
    __syncthreads();
#pragma unroll
    for (int u=0;u<2;u++)
#pragma unroll
      for (int nt=0;nt<4;nt++){
        int node = nt*16 + ln;
        unsigned int lo=0, hi=0;
#pragma unroll
        for (int r=0;r<4;r++){
          float iv = acc[0][u][nt][r];
          float fv = acc[1][u][nt][r];
          float gv = acc[2][u][nt][r];
          float ov = acc[3][u][nt][r];
          float cn = sigmoidf_(fv)*c[u][nt][r] + sigmoidf_(iv)*tanh_fast(gv);
          c[u][nt][r] = cn;
          float h = sigmoidf_(ov)*tanh_fast(cn);
          unsigned int hb = f2bf(h);
          if (r<2) lo |= hb << (16*r); else hi |= hb << (16*(r-2));
        }
        int kb = (w*32 + u*16 + q*4)*2;
        uint2* p = (uint2*)((char*)hs + node*256 + (kb ^ ((node&7)<<4)));
        uint2 pv; pv.x = lo; pv.y = hi;
        *p = pv;
      }
    __syncthreads();
  }

#pragma unroll
  for (int u=0;u<2;u++)
#pragma unroll
    for (int nt=0;nt<4;nt++){
      int node = nt*16 + ln;
      if (n0+node < n){
        int kb = (w*32 + u*16 + q*4)*2;
        const uint2* p = (const uint2*)((const char*)hs + node*256 + (kb ^ ((node&7)<<4)));
        *(uint2*)(aggb + (size_t)(n0+node)*128 + w*32 + u*16 + q*4) = *p;
      }
    }
}

// Edge MLP, MFMA: 4 dst nodes (64 edges) per block, 4 waves; wave w owns edges [w*16, w*16+16).
// No inter-wave data flow after staging -> single barrier.
__global__ __launch_bounds__(256,2) void k_edge2(
    const float* __restrict__ HsHd,   // [N][256] f32: cols 0..127 Hs, 128..255 Hd
    const float* __restrict__ ea,     // [E][16]
    const int* __restrict__ src,
    const unsigned short* __restrict__ W1eh, const unsigned short* __restrict__ W1el, // [128][16]
    const unsigned short* __restrict__ W2h,  const unsigned short* __restrict__ W2l,  // [64][128]
    const unsigned short* __restrict__ W3p,  // [16][64]
    const float* __restrict__ b1, const float* __restrict__ b2, const float* __restrict__ b3,
    float* __restrict__ out)
{
  __shared__ unsigned short out1h[64*128];  // 16 KB, row stride 256B, SWZ
  __shared__ unsigned short out1l[64*128];  // 16 KB
  __shared__ unsigned short e2h[64*64];     // 8 KB, row stride 128B, SWZ
  __shared__ unsigned short e2l[64*64];     // 8 KB
  __shared__ unsigned short ea2[64*56];     // rows: [0..15]=hi, [16..31]=lo, pad to 56 (112B, 16B-mult)
  __shared__ float hd[4*128];
  __shared__ int srcs[64];

  const int t = threadIdx.x;
  const int w = t>>6, l = t&63, ln = l&15, q = l>>4;
  const int nblk = blockIdx.x;
  const size_t e0 = (size_t)nblk*64;

  for (int i=t;i<1024;i+=256){
    int e=i>>4, k=i&15;
    float v = ea[(e0+e)*16 + k];
    unsigned short hi = f2bf(v);
    ea2[e*56 + k] = hi;
    ea2[e*56 + 16 + k] = f2bf(v - bf2f(hi));
  }
  for (int i=t;i<512;i+=256){
    int d=i>>7, j=i&127;
    hd[d*128+j] = HsHd[((size_t)nblk*4+d)*256 + 128 + j];
  }
  if (t<64) srcs[t] = src[e0+t];
  __syncthreads();

  // ---- phase 1: out1[edge][0..128) = relu(Hs[src]+Hd+b1 + ea@W1e^T), hi/lo bf16 to LDS
  {
    // A-frag K=32: k<16 -> ea_hi[k], k>=16 -> ea_lo[k-16]; contiguous in ea2 row
    bfrag Aea = *(const bfrag*)&ea2[(w*16+ln)*56 + q*8];
#pragma unroll
    for (int nt=0;nt<8;nt++){
      int j = nt*16 + ln;
      // B[k][n]=W1e[j][k&15] duplicated across K halves -> (hi+lo)@W
      bfrag B1 = *(const bfrag*)(W1eh + (size_t)j*16 + (q&1)*8);
      bfrag B2 = *(const bfrag*)(W1el + (size_t)j*16 + (q&1)*8);
      float b1v = b1[j];
      float hdv = hd[w*128 + j];
      f32x4 acc;
#pragma unroll
      for (int r=0;r<4;r++){
        int edge = w*16 + q*4 + r;
        acc[r] = b1v + hdv + HsHd[(size_t)srcs[edge]*256 + j];
      }
      acc = __builtin_amdgcn_mfma_f32_16x16x32_bf16(Aea, B1, acc, 0,0,0);
      acc = __builtin_amdgcn_mfma_f32_16x16x32_bf16(Aea, B2, acc, 0,0,0);
#pragma unroll
      for (int r=0;r<4;r++){
        int row = w*16 + q*4 + r;
        float v = fmaxf(acc[r], 0.f);
        unsigned short hi = f2bf(v);
        float lo = v - bf2f(hi);
        int byt = row*256 + ((j*2) ^ SWZ(row));
        *(unsigned short*)((char*)out1h + byt) = hi;
        *(unsigned short*)((char*)out1l + byt) = f2bf(lo);
      }
    }
  }

  // ---- phase 2: e2[edge][0..64) = relu(out1@W2^T + b2); wave reads only its own rows
  {
    f32x4 acc[4];
#pragma unroll
    for (int nt=0;nt<4;nt++){ float bv = b2[nt*16+ln]; acc[nt] = (f32x4){bv,bv,bv,bv}; }
    int arow = w*16 + ln;
#pragma unroll
    for (int ks=0;ks<4;ks++){
      int byt = arow*256 + ((ks*64 + q*16) ^ SWZ(arow));
      bfrag Ah = *(const bfrag*)((char*)out1h + byt);
      bfrag Al = *(const bfrag*)((char*)out1l + byt);
#pragma unroll
      for (int nt=0;nt<4;nt++){
        int j = nt*16 + ln;
        bfrag Bh = *(const bfrag*)(W2h + (size_t)j*128 + ks*32 + q*8);
        bfrag Bl = *(const bfrag*)(W2l + (size_t)j*128 + ks*32 + q*8);
        acc[nt] = __builtin_amdgcn_mfma_f32_16x16x32_bf16(Ah, Bh, acc[nt], 0,0,0);
        acc[nt] = __builtin_amdgcn_mfma_f32_16x16x32_bf16(Al, Bh, acc[nt], 0,0,0);
        acc[nt] = __builtin_amdgcn_mfma_f32_16x16x32_bf16(Ah, Bl, acc[nt], 0,0,0);
      }
    }
#pragma unroll
    for (int nt=0;nt<4;nt++)
#pragma unroll
      for (int r=0;r<4;r++){
        int row = w*16 + q*4 + r;
        int j = nt*16 + ln;
        float v = fmaxf(acc[nt][r], 0.f);
        unsigned short hi = f2bf(v);
        float lo = v - bf2f(hi);
        int byt = row*128 + ((j*2) ^ SWZ(row));
        *(unsigned short*)((char*)e2h + byt) = hi;
        *(unsigned short*)((char*)e2l + byt) = f2bf(lo);
      }
  }

  // ---- phase 3: out[edge][0..2) = e2@W3^T + b3 (W3 zero-padded to 16 rows)
  {
    float b3v = (ln<2) ? b3[ln] : 0.f;
    f32x4 acc = (f32x4){b3v,b3v,b3v,b3v};
    int arow = w*16 + ln;
#pragma unroll
    for (int ks=0;ks<2;ks++){
      int byt = arow*128 + ((ks*64 + q*16) ^ SWZ(arow));
      bfrag Ah = *(const bfrag*)((char*)e2h + byt);
      bfrag Al = *(const bfrag*)((char*)e2l + byt);
      bfrag B  = *(const bfrag*)(W3p + (size_t)ln*64 + ks*32 + q*8);
      acc = __builtin_amdgcn_mfma_f32_16x16x32_bf16(Ah, B, acc, 0,0,0);
      acc = __builtin_amdgcn_mfma_f32_16x16x32_bf16(Al, B, acc, 0,0,0);
    }
    if (ln < 2){
#pragma unroll
      for (int r=0;r<4;r++){
        int row = w*16 + q*4 + r;
        out[(e0 + row)*2 + ln] = acc[r];
      }
    }
  }
}

extern "C" void kernel_launch(void* const* d_in, const int* in_sizes, int n_in,
                              void* d_out, int out_size, void* d_ws, size_t ws_size,
                              hipStream_t stream) {
  const float* x    = (const float*)d_in[0];
  const int*   eidx = (const int*)  d_in[1];
  const float* eatt = (const float*)d_in[2];
  const float* Wih  = (const float*)d_in[3];
  const float* Whh  = (const float*)d_in[4];
  const float* bih  = (const float*)d_in[5];
  const float* bhh  = (const float*)d_in[6];
  const float* WlL  = (const float*)d_in[7];
  const float* blL  = (const float*)d_in[8];
  const float* WrL  = (const float*)d_in[9];
  const float* W1   = (const float*)d_in[10];
  const float* b1   = (const float*)d_in[11];
  const float* W2   = (const float*)d_in[12];
  const float* b2   = (const float*)d_in[13];
  const float* W3   = (const float*)d_in[14];
  const float* b3   = (const float*)d_in[15];
  const int*   src  = eidx;

  char* p = (char*)d_ws;
  unsigned short* Gb = (unsigned short*)p;      // [NN][512] bf16
  float* HsHd        = (float*)p;               // [NN][256] f32 (aliases Gb; Gb dead by then)
  p += (size_t)NN*512*2;
  unsigned short* xb   = (unsigned short*)p; p += (size_t)NN*128*2;
  unsigned short* hb1  = (unsigned short*)p; p += (size_t)NN*128*2;
  unsigned short* hb2  = (unsigned short*)p; p += (size_t)NN*128*2;
  unsigned short* aggb = (unsigned short*)p; p += (size_t)NN*128*2;
  unsigned short* Wihb = (unsigned short*)p; p += (size_t)3*512*128*2;
  unsigned short* Whhb = (unsigned short*)p; p += (size_t)3*512*128*2;
  unsigned short* Wlb  = (unsigned short*)p; p += (size_t)3*128*128*2;
  unsigned short* Wrb  = (unsigned short*)p; p += (size_t)3*128*128*2;
  unsigned short* W1nb = (unsigned short*)p; p += (size_t)256*128*2;
  unsigned short* W1eh = (unsigned short*)p; p += 2048*2;
  unsigned short* W1el = (unsigned short*)p; p += 2048*2;
  unsigned short* W2h  = (unsigned short*)p; p += 8192*2;
  unsigned short* W2l  = (unsigned short*)p; p += 8192*2;
  unsigned short* W3p  = (unsigned short*)p; p += 1024*2;

  dim3 blk(256);
  const int nb = (NN + 63)/64;

  k_cvt<<<(NN*128+255)/256, blk, 0, stream>>>(x, xb, NN*128);
  k_cvt<<<(3*512*128+255)/256, blk, 0, stream>>>(Wih, Wihb, 3*512*128);
  k_cvt<<<(3*512*128+255)/256, blk, 0, stream>>>(Whh, Whhb, 3*512*128);
  k_cvt<<<(3*128*128+255)/256, blk, 0, stream>>>(WlL, Wlb, 3*128*128);
  k_cvt<<<(3*128*128+255)/256, blk, 0, stream>>>(WrL, Wrb, 3*128*128);
  k_cvt2<<<(128*128+255)/256, blk, 0, stream>>>(W1, W1nb,           272, 0,   128, 128*128);
  k_cvt2<<<(128*128+255)/256, blk, 0, stream>>>(W1, W1nb+128*128,   272, 128, 128, 128*128);
  k_prep_edge<<<(11264+255)/256, blk, 0, stream>>>(W1, W2, W3, W1eh, W1el, W2h, W2l, W3p);

  const unsigned short* hin = xb;
  unsigned short* houts[3] = {hb1, hb2, hb1};
  for (int l = 0; l < 3; l++){
    k_bgemm<<<dim3(nb,4),blk,0,stream>>>(hin, nullptr,
        Wihb + (size_t)l*512*128, nullptr,
        bih + (size_t)l*512, bhh + (size_t)l*512,
        nullptr, Gb, 512, 0, NN);
    k_lstm2<<<dim3(nb),blk,0,stream>>>(Gb, src, Whhb + (size_t)l*512*128, aggb, NN);
    k_bgemm<<<dim3(nb,1),blk,0,stream>>>(aggb, hin,
        Wlb + (size_t)l*128*128, Wrb + (size_t)l*128*128,
        blL + (size_t)l*128, nullptr,
        nullptr, houts[l], 128, 1, NN);
    hin = houts[l];
  }
  // hin == hb1 (final node features). HsHd = h @ [W1[:, :128] ; W1[:, 128:256]]^T
  k_bgemm<<<dim3(nb,2),blk,0,stream>>>(hin, nullptr, W1nb, nullptr,
                                       nullptr, nullptr, HsHd, nullptr, 256, 0, NN);
  k_edge2<<<dim3(NN/4),blk,0,stream>>>(HsHd, eatt, src, W1eh, W1el, W2h, W2l, W3p,
                                       b1, b2, b3, (float*)d_out);
}

// Round 4
// 1887.703 us; speedup vs baseline: 4.9192x; 1.1500x over previous
//
#include <hip/hip_runtime.h>
#include <hip/hip_bf16.h>

#define NN 50000
#define DEG 16

typedef __attribute__((ext_vector_type(8))) short bfrag;   // 8 x bf16 bits (16B)
typedef __attribute__((ext_vector_type(4))) float f32x4;

__device__ __forceinline__ float bf2f(unsigned int u){ return __uint_as_float(u<<16); }
__device__ __forceinline__ unsigned short f2bf(float x){
  unsigned int u = __float_as_uint(x);
  unsigned int r = (u + 0x7fffu + ((u>>16)&1u)) >> 16;
  return (unsigned short)r;
}
__device__ __forceinline__ float fast_rcp(float x){ return __builtin_amdgcn_rcpf(x); }
__device__ __forceinline__ float sigmoidf_(float x){ return fast_rcp(1.f + __expf(-x)); }
__device__ __forceinline__ float tanh_fast(float x){
  float e = __expf(-2.f*fabsf(x));
  float r = (1.f - e)*fast_rcp(1.f + e);
  return copysignf(r, x);
}

#define SWZ(row) (((((row) ^ ((row)>>3)) & 7)) << 4)

__global__ void k_cvt(const float* __restrict__ in, unsigned short* __restrict__ out, int n){
  int i = blockIdx.x*256 + threadIdx.x;
  if (i < n) out[i] = f2bf(in[i]);
}

__global__ void k_cvt2(const float* __restrict__ in, unsigned short* __restrict__ out,
                       int stride, int off, int cols, int total){
  int i = blockIdx.x*256 + threadIdx.x;
  if (i < total){
    int r = i / cols, c = i - r*cols;
    out[i] = f2bf(in[(size_t)r*stride + off + c]);
  }
}

__global__ void k_prep_edge(const float* __restrict__ W1, const float* __restrict__ W2,
                            const float* __restrict__ W3,
                            unsigned short* __restrict__ W1eh, unsigned short* __restrict__ W1el,
                            unsigned short* __restrict__ W2h, unsigned short* __restrict__ W2l,
                            unsigned short* __restrict__ W3p)
{
  int i = blockIdx.x*256 + threadIdx.x;
  if (i < 8192){
    float v = W2[i];
    unsigned short hi = f2bf(v);
    W2h[i] = hi; W2l[i] = f2bf(v - bf2f(hi));
  } else if (i < 10240){
    int k = i - 8192; int j = k >> 4, kk = k & 15;
    float v = W1[(size_t)j*272 + 256 + kk];
    unsigned short hi = f2bf(v);
    W1eh[k] = hi; W1el[k] = f2bf(v - bf2f(hi));
  } else if (i < 11264){
    int k = i - 10240; int nr = k >> 6, c = k & 63;
    W3p[k] = f2bf(nr < 2 ? W3[nr*64 + c] : 0.f);
  }
}

// bf16 MFMA gemm (unchanged from R3).
__global__ __launch_bounds__(256,4) void k_bgemm(
    const unsigned short* __restrict__ Ab, const unsigned short* __restrict__ A2b,
    const unsigned short* __restrict__ Wb, const unsigned short* __restrict__ W2b,
    const float* __restrict__ bias, const float* __restrict__ bias2,
    float* __restrict__ outF, unsigned short* __restrict__ outB,
    int ostride, int dorelu, int n)
{
  const int t  = threadIdx.x;
  const int w  = t >> 6;
  const int l  = t & 63;
  const int ln = l & 15, q = l >> 4;
  const int n0 = blockIdx.x*64;
  const int j0 = blockIdx.y*128 + w*32;

  int nodeM[4];
#pragma unroll
  for (int mt=0;mt<4;mt++){ int nd = n0 + mt*16 + ln; nodeM[mt] = nd < n ? nd : n-1; }

  f32x4 acc[4][2];
#pragma unroll
  for (int mt=0;mt<4;mt++)
#pragma unroll
    for (int nt=0;nt<2;nt++) acc[mt][nt] = (f32x4){0.f,0.f,0.f,0.f};

  auto pass = [&](const unsigned short* __restrict__ Ap, const unsigned short* __restrict__ Wp){
#pragma unroll
    for (int ks=0;ks<4;ks++){
      bfrag Af[4], Bf[2];
#pragma unroll
      for (int mt=0;mt<4;mt++)
        Af[mt] = *(const bfrag*)(Ap + (size_t)nodeM[mt]*128 + ks*32 + q*8);
#pragma unroll
      for (int nt=0;nt<2;nt++)
        Bf[nt] = *(const bfrag*)(Wp + (size_t)(j0 + nt*16 + ln)*128 + ks*32 + q*8);
#pragma unroll
      for (int mt=0;mt<4;mt++)
#pragma unroll
        for (int nt=0;nt<2;nt++)
          acc[mt][nt] = __builtin_amdgcn_mfma_f32_16x16x32_bf16(Af[mt], Bf[nt], acc[mt][nt], 0,0,0);
    }
  };
  pass(Ab, Wb);
  if (A2b) pass(A2b, W2b);

#pragma unroll
  for (int nt=0;nt<2;nt++){
    int j = j0 + nt*16 + ln;
    float bv = bias ? bias[j] : 0.f;
    if (bias2) bv += bias2[j];
#pragma unroll
    for (int mt=0;mt<4;mt++)
#pragma unroll
      for (int r=0;r<4;r++){
        int row = n0 + mt*16 + q*4 + r;
        if (row < n){
          float v = acc[mt][nt][r] + bv;
          if (dorelu) v = fmaxf(v, 0.f);
          if (outF) outF[(size_t)row*ostride + j] = v;
          if (outB) outB[(size_t)row*ostride + j] = f2bf(v);
        }
      }
  }
}

// MFMA LSTM v3: 512 thr (8 waves), 64 nodes/block. Wave w owns hidden units
// [w*16, w*16+16) across all 4 gates -> A-frags 64 VGPR, acc 64 VGPR.
// G[src] folded at ACTIVATION (not acc-init): the 16 8B gather loads issue at
// the top of each step and complete under the MFMA phase.
__global__ __launch_bounds__(512,2) void k_lstm3(
    const unsigned short* __restrict__ G,    // [n][512] bf16
    const int* __restrict__ src,             // [n*16]
    const unsigned short* __restrict__ Whhb, // [512][128] bf16
    unsigned short* __restrict__ aggb, int n)
{
  __shared__ unsigned short hs[64*128];      // 16 KB, row=node (256B), swizzled
  __shared__ int srcs[64*17];
  const int t  = threadIdx.x;
  const int w  = t >> 6;                     // 0..7
  const int l  = t & 63;
  const int ln = l & 15;
  const int q  = l >> 4;
  const int n0 = blockIdx.x * 64;

  for (int i = t; i < 1024; i += 512){
    int nl = i >> 4, st = i & 15;
    srcs[nl*17 + st] = (n0+nl < n) ? src[(size_t)(n0+nl)*16 + st] : 0;
  }
  for (int i = t; i < 64*128; i += 512) hs[i] = 0;

  // A-frags: lane ln provides A row m=ln -> gate T*128 + w*16 + ln
  bfrag A[4][4];   // [T][ks], 64 VGPR
#pragma unroll
  for (int T=0;T<4;T++)
#pragma unroll
    for (int ks=0;ks<4;ks++)
      A[T][ks] = *(const bfrag*)(Whhb + (size_t)(T*128 + w*16 + ln)*128 + ks*32 + q*8);

  float c[4][4];   // [nt][r]
#pragma unroll
  for (int nt=0;nt<4;nt++)
#pragma unroll
    for (int r=0;r<4;r++) c[nt][r]=0.f;

  __syncthreads();

  for (int step=0; step<16; step++){
    // --- issue G gathers for this step (consumed after MFMA phase) ---
    uint2 gv[4][4];   // [nt][T], 32 VGPR
#pragma unroll
    for (int nt=0;nt<4;nt++){
      int node = nt*16 + ln;
      const unsigned short* Grow = G + (size_t)srcs[node*17 + step]*512;
#pragma unroll
      for (int T=0;T<4;T++)
        gv[nt][T] = *(const uint2*)(Grow + T*128 + w*16 + q*4);
    }

    f32x4 acc[4][4];  // [T][nt]
#pragma unroll
    for (int T=0;T<4;T++)
#pragma unroll
      for (int nt=0;nt<4;nt++) acc[T][nt] = (f32x4){0.f,0.f,0.f,0.f};

    if (step > 0){
      __syncthreads();    // h writes from prev step visible
#pragma unroll
      for (int np=0; np<2; np++){
        bfrag B[2][4];
#pragma unroll
        for (int ntl=0; ntl<2; ntl++){
          int node = (np*2+ntl)*16 + ln;
#pragma unroll
          for (int ks=0;ks<4;ks++)
            B[ntl][ks] = *(const bfrag*)((const char*)hs + node*256 +
                          (((ks*32+q*8)*2) ^ ((node&7)<<4)));
        }
#pragma unroll
        for (int T=0;T<4;T++)
#pragma unroll
          for (int ntl=0; ntl<2; ntl++)
#pragma unroll
            for (int ks=0;ks<4;ks++)
              acc[T][np*2+ntl] = __builtin_amdgcn_mfma_f32_16x16x32_bf16(
                  A[T][ks], B[ntl][ks], acc[T][np*2+ntl], 0, 0, 0);
      }
      __syncthreads();    // all hs reads done before overwrite
    }

    // --- activation: gates = acc + G[src]; h -> LDS (and aggb at last step) ---
#pragma unroll
    for (int nt=0;nt<4;nt++){
      int node = nt*16 + ln;
      unsigned int lo=0, hi=0;
#pragma unroll
      for (int r=0;r<4;r++){
        unsigned int gi = (r<2) ? (gv[nt][0].x >> (16*r))     : (gv[nt][0].y >> (16*(r-2)));
        unsigned int gf = (r<2) ? (gv[nt][1].x >> (16*r))     : (gv[nt][1].y >> (16*(r-2)));
        unsigned int gg = (r<2) ? (gv[nt][2].x >> (16*r))     : (gv[nt][2].y >> (16*(r-2)));
        unsigned int go = (r<2) ? (gv[nt][3].x >> (16*r))     : (gv[nt][3].y >> (16*(r-2)));
        float iv = acc[0][nt][r] + bf2f(gi & 0xffffu);
        float fv = acc[1][nt][r] + bf2f(gf & 0xffffu);
        float gvl= acc[2][nt][r] + bf2f(gg & 0xffffu);
        float ov = acc[3][nt][r] + bf2f(go & 0xffffu);
        float cn = sigmoidf_(fv)*c[nt][r] + sigmoidf_(iv)*tanh_fast(gvl);
        c[nt][r] = cn;
        float h = sigmoidf_(ov)*tanh_fast(cn);
        unsigned int hb = f2bf(h);
        if (r<2) lo |= hb << (16*r); else hi |= hb << (16*(r-2));
      }
      int kb = (w*16 + q*4)*2;
      uint2 pv; pv.x = lo; pv.y = hi;
      *(uint2*)((char*)hs + node*256 + (kb ^ ((node&7)<<4))) = pv;
      if (step == 15 && n0+node < n)
        *(uint2*)(aggb + (size_t)(n0+node)*128 + w*16 + q*4) = pv;
    }
    __syncthreads();   // h writes visible for next step's reads
  }
}

// Edge MLP, MFMA (unchanged from R3).
__global__ __launch_bounds__(256,2) void k_edge2(
    const float* __restrict__ HsHd,
    const float* __restrict__ ea,
    const int* __restrict__ src,
    const unsigned short* __restrict__ W1eh, const unsigned short* __restrict__ W1el,
    const unsigned short* __restrict__ W2h,  const unsigned short* __restrict__ W2l,
    const unsigned short* __restrict__ W3p,
    const float* __restrict__ b1, const float* __restrict__ b2, const float* __restrict__ b3,
    float* __restrict__ out)
{
  __shared__ unsigned short out1h[64*128];
  __shared__ unsigned short out1l[64*128];
  __shared__ unsigned short e2h[64*64];
  __shared__ unsigned short e2l[64*64];
  __shared__ unsigned short ea2[64*56];
  __shared__ float hd[4*128];
  __shared__ int srcs[64];

  const int t = threadIdx.x;
  const int w = t>>6, l = t&63, ln = l&15, q = l>>4;
  const int nblk = blockIdx.x;
  const size_t e0 = (size_t)nblk*64;

  for (int i=t;i<1024;i+=256){
    int e=i>>4, k=i&15;
    float v = ea[(e0+e)*16 + k];
    unsigned short hi = f2bf(v);
    ea2[e*56 + k] = hi;
    ea2[e*56 + 16 + k] = f2bf(v - bf2f(hi));
  }
  for (int i=t;i<512;i+=256){
    int d=i>>7, j=i&127;
    hd[d*128+j] = HsHd[((size_t)nblk*4+d)*256 + 128 + j];
  }
  if (t<64) srcs[t] = src[e0+t];
  __syncthreads();

  {
    bfrag Aea = *(const bfrag*)&ea2[(w*16+ln)*56 + q*8];
#pragma unroll
    for (int nt=0;nt<8;nt++){
      int j = nt*16 + ln;
      bfrag B1 = *(const bfrag*)(W1eh + (size_t)j*16 + (q&1)*8);
      bfrag B2 = *(const bfrag*)(W1el + (size_t)j*16 + (q&1)*8);
      float b1v = b1[j];
      float hdv = hd[w*128 + j];
      f32x4 acc;
#pragma unroll
      for (int r=0;r<4;r++){
        int edge = w*16 + q*4 + r;
        acc[r] = b1v + hdv + HsHd[(size_t)srcs[edge]*256 + j];
      }
      acc = __builtin_amdgcn_mfma_f32_16x16x32_bf16(Aea, B1, acc, 0,0,0);
      acc = __builtin_amdgcn_mfma_f32_16x16x32_bf16(Aea, B2, acc, 0,0,0);
#pragma unroll
      for (int r=0;r<4;r++){
        int row = w*16 + q*4 + r;
        float v = fmaxf(acc[r], 0.f);
        unsigned short hi = f2bf(v);
        float lo = v - bf2f(hi);
        int byt = row*256 + ((j*2) ^ SWZ(row));
        *(unsigned short*)((char*)out1h + byt) = hi;
        *(unsigned short*)((char*)out1l + byt) = f2bf(lo);
      }
    }
  }

  {
    f32x4 acc[4];
#pragma unroll
    for (int nt=0;nt<4;nt++){ float bv = b2[nt*16+ln]; acc[nt] = (f32x4){bv,bv,bv,bv}; }
    int arow = w*16 + ln;
#pragma unroll
    for (int ks=0;ks<4;ks++){
      int byt = arow*256 + ((ks*64 + q*16) ^ SWZ(arow));
      bfrag Ah = *(const bfrag*)((char*)out1h + byt);
      bfrag Al = *(const bfrag*)((char*)out1l + byt);
#pragma unroll
      for (int nt=0;nt<4;nt++){
        int j = nt*16 + ln;
        bfrag Bh = *(const bfrag*)(W2h + (size_t)j*128 + ks*32 + q*8);
        bfrag Bl = *(const bfrag*)(W2l + (size_t)j*128 + ks*32 + q*8);
        acc[nt] = __builtin_amdgcn_mfma_f32_16x16x32_bf16(Ah, Bh, acc[nt], 0,0,0);
        acc[nt] = __builtin_amdgcn_mfma_f32_16x16x32_bf16(Al, Bh, acc[nt], 0,0,0);
        acc[nt] = __builtin_amdgcn_mfma_f32_16x16x32_bf16(Ah, Bl, acc[nt], 0,0,0);
      }
    }
#pragma unroll
    for (int nt=0;nt<4;nt++)
#pragma unroll
      for (int r=0;r<4;r++){
        int row = w*16 + q*4 + r;
        int j = nt*16 + ln;
        float v = fmaxf(acc[nt][r], 0.f);
        unsigned short hi = f2bf(v);
        float lo = v - bf2f(hi);
        int byt = row*128 + ((j*2) ^ SWZ(row));
        *(unsigned short*)((char*)e2h + byt) = hi;
        *(unsigned short*)((char*)e2l + byt) = f2bf(lo);
      }
  }

  {
    float b3v = (ln<2) ? b3[ln] : 0.f;
    f32x4 acc = (f32x4){b3v,b3v,b3v,b3v};
    int arow = w*16 + ln;
#pragma unroll
    for (int ks=0;ks<2;ks++){
      int byt = arow*128 + ((ks*64 + q*16) ^ SWZ(arow));
      bfrag Ah = *(const bfrag*)((char*)e2h + byt);
      bfrag Al = *(const bfrag*)((char*)e2l + byt);
      bfrag B  = *(const bfrag*)(W3p + (size_t)ln*64 + ks*32 + q*8);
      acc = __builtin_amdgcn_mfma_f32_16x16x32_bf16(Ah, B, acc, 0,0,0);
      acc = __builtin_amdgcn_mfma_f32_16x16x32_bf16(Al, B, acc, 0,0,0);
    }
    if (ln < 2){
#pragma unroll
      for (int r=0;r<4;r++){
        int row = w*16 + q*4 + r;
        out[(e0 + row)*2 + ln] = acc[r];
      }
    }
  }
}

extern "C" void kernel_launch(void* const* d_in, const int* in_sizes, int n_in,
                              void* d_out, int out_size, void* d_ws, size_t ws_size,
                              hipStream_t stream) {
  const float* x    = (const float*)d_in[0];
  const int*   eidx = (const int*)  d_in[1];
  const float* eatt = (const float*)d_in[2];
  const float* Wih  = (const float*)d_in[3];
  const float* Whh  = (const float*)d_in[4];
  const float* bih  = (const float*)d_in[5];
  const float* bhh  = (const float*)d_in[6];
  const float* WlL  = (const float*)d_in[7];
  const float* blL  = (const float*)d_in[8];
  const float* WrL  = (const float*)d_in[9];
  const float* W1   = (const float*)d_in[10];
  const float* b1   = (const float*)d_in[11];
  const float* W2   = (const float*)d_in[12];
  const float* b2   = (const float*)d_in[13];
  const float* W3   = (const float*)d_in[14];
  const float* b3   = (const float*)d_in[15];
  const int*   src  = eidx;

  char* p = (char*)d_ws;
  unsigned short* Gb = (unsigned short*)p;      // [NN][512] bf16
  float* HsHd        = (float*)p;               // [NN][256] f32 (aliases Gb; Gb dead by then)
  p += (size_t)NN*512*2;
  unsigned short* xb   = (unsigned short*)p; p += (size_t)NN*128*2;
  unsigned short* hb1  = (unsigned short*)p; p += (size_t)NN*128*2;
  unsigned short* hb2  = (unsigned short*)p; p += (size_t)NN*128*2;
  unsigned short* aggb = (unsigned short*)p; p += (size_t)NN*128*2;
  unsigned short* Wihb = (unsigned short*)p; p += (size_t)3*512*128*2;
  unsigned short* Whhb = (unsigned short*)p; p += (size_t)3*512*128*2;
  unsigned short* Wlb  = (unsigned short*)p; p += (size_t)3*128*128*2;
  unsigned short* Wrb  = (unsigned short*)p; p += (size_t)3*128*128*2;
  unsigned short* W1nb = (unsigned short*)p; p += (size_t)256*128*2;
  unsigned short* W1eh = (unsigned short*)p; p += 2048*2;
  unsigned short* W1el = (unsigned short*)p; p += 2048*2;
  unsigned short* W2h  = (unsigned short*)p; p += 8192*2;
  unsigned short* W2l  = (unsigned short*)p; p += 8192*2;
  unsigned short* W3p  = (unsigned short*)p; p += 1024*2;

  dim3 blk(256);
  const int nb = (NN + 63)/64;

  k_cvt<<<(NN*128+255)/256, blk, 0, stream>>>(x, xb, NN*128);
  k_cvt<<<(3*512*128+255)/256, blk, 0, stream>>>(Wih, Wihb, 3*512*128);
  k_cvt<<<(3*512*128+255)/256, blk, 0, stream>>>(Whh, Whhb, 3*512*128);
  k_cvt<<<(3*128*128+255)/256, blk, 0, stream>>>(WlL, Wlb, 3*128*128);
  k_cvt<<<(3*128*128+255)/256, blk, 0, stream>>>(WrL, Wrb, 3*128*128);
  k_cvt2<<<(128*128+255)/256, blk, 0, stream>>>(W1, W1nb,           272, 0,   128, 128*128);
  k_cvt2<<<(128*128+255)/256, blk, 0, stream>>>(W1, W1nb+128*128,   272, 128, 128, 128*128);
  k_prep_edge<<<(11264+255)/256, blk, 0, stream>>>(W1, W2, W3, W1eh, W1el, W2h, W2l, W3p);

  const unsigned short* hin = xb;
  unsigned short* houts[3] = {hb1, hb2, hb1};
  for (int l = 0; l < 3; l++){
    k_bgemm<<<dim3(nb,4),blk,0,stream>>>(hin, nullptr,
        Wihb + (size_t)l*512*128, nullptr,
        bih + (size_t)l*512, bhh + (size_t)l*512,
        nullptr, Gb, 512, 0, NN);
    k_lstm3<<<dim3(nb),dim3(512),0,stream>>>(Gb, src, Whhb + (size_t)l*512*128, aggb, NN);
    k_bgemm<<<dim3(nb,1),blk,0,stream>>>(aggb, hin,
        Wlb + (size_t)l*128*128, Wrb + (size_t)l*128*128,
        blL + (size_t)l*128, nullptr,
        nullptr, houts[l], 128, 1, NN);
    hin = houts[l];
  }
  k_bgemm<<<dim3(nb,2),blk,0,stream>>>(hin, nullptr, W1nb, nullptr,
                                       nullptr, nullptr, HsHd, nullptr, 256, 0, NN);
  k_edge2<<<dim3(NN/4),blk,0,stream>>>(HsHd, eatt, src, W1eh, W1el, W2h, W2l, W3p,
                                       b1, b2, b3, (float*)d_out);
}

// Round 5
// 1524.269 us; speedup vs baseline: 6.0920x; 1.2384x over previous
//
#include <hip/hip_runtime.h>
#include <hip/hip_bf16.h>

#define NN 50000
#define DEG 16

typedef __attribute__((ext_vector_type(8))) short bfrag;   // 8 x bf16 bits (16B)
typedef __attribute__((ext_vector_type(4))) float f32x4;

__device__ __forceinline__ float bf2f(unsigned int u){ return __uint_as_float(u<<16); }
__device__ __forceinline__ unsigned short f2bf(float x){
  unsigned int u = __float_as_uint(x);
  unsigned int r = (u + 0x7fffu + ((u>>16)&1u)) >> 16;
  return (unsigned short)r;
}
__device__ __forceinline__ float fast_rcp(float x){ return __builtin_amdgcn_rcpf(x); }
__device__ __forceinline__ float sigmoidf_(float x){ return fast_rcp(1.f + __expf(-x)); }
__device__ __forceinline__ float tanh_fast(float x){
  float e = __expf(-2.f*fabsf(x));
  float r = (1.f - e)*fast_rcp(1.f + e);
  return copysignf(r, x);
}

#define SWZ(row) (((((row) ^ ((row)>>3)) & 7)) << 4)

// global->LDS DMA, 16B per lane; LDS dest is wave-uniform base + lane*16 (linear).
#define GLDS16(g, l) __builtin_amdgcn_global_load_lds( \
    (const __attribute__((address_space(1))) unsigned int*)(g), \
    (__attribute__((address_space(3))) unsigned int*)(l), 16, 0, 0)

__global__ void k_cvt(const float* __restrict__ in, unsigned short* __restrict__ out, int n){
  int i = blockIdx.x*256 + threadIdx.x;
  if (i < n) out[i] = f2bf(in[i]);
}

__global__ void k_cvt2(const float* __restrict__ in, unsigned short* __restrict__ out,
                       int stride, int off, int cols, int total){
  int i = blockIdx.x*256 + threadIdx.x;
  if (i < total){
    int r = i / cols, c = i - r*cols;
    out[i] = f2bf(in[(size_t)r*stride + off + c]);
  }
}

__global__ void k_prep_edge(const float* __restrict__ W1, const float* __restrict__ W2,
                            const float* __restrict__ W3,
                            unsigned short* __restrict__ W1eh, unsigned short* __restrict__ W1el,
                            unsigned short* __restrict__ W2h, unsigned short* __restrict__ W2l,
                            unsigned short* __restrict__ W3p)
{
  int i = blockIdx.x*256 + threadIdx.x;
  if (i < 8192){
    float v = W2[i];
    unsigned short hi = f2bf(v);
    W2h[i] = hi; W2l[i] = f2bf(v - bf2f(hi));
  } else if (i < 10240){
    int k = i - 8192; int j = k >> 4, kk = k & 15;
    float v = W1[(size_t)j*272 + 256 + kk];
    unsigned short hi = f2bf(v);
    W1eh[k] = hi; W1el[k] = f2bf(v - bf2f(hi));
  } else if (i < 11264){
    int k = i - 10240; int nr = k >> 6, c = k & 63;
    W3p[k] = f2bf(nr < 2 ? W3[nr*64 + c] : 0.f);
  }
}

// bf16 MFMA gemm (unchanged).
__global__ __launch_bounds__(256,4) void k_bgemm(
    const unsigned short* __restrict__ Ab, const unsigned short* __restrict__ A2b,
    const unsigned short* __restrict__ Wb, const unsigned short* __restrict__ W2b,
    const float* __restrict__ bias, const float* __restrict__ bias2,
    float* __restrict__ outF, unsigned short* __restrict__ outB,
    int ostride, int dorelu, int n)
{
  const int t  = threadIdx.x;
  const int w  = t >> 6;
  const int l  = t & 63;
  const int ln = l & 15, q = l >> 4;
  const int n0 = blockIdx.x*64;
  const int j0 = blockIdx.y*128 + w*32;

  int nodeM[4];
#pragma unroll
  for (int mt=0;mt<4;mt++){ int nd = n0 + mt*16 + ln; nodeM[mt] = nd < n ? nd : n-1; }

  f32x4 acc[4][2];
#pragma unroll
  for (int mt=0;mt<4;mt++)
#pragma unroll
    for (int nt=0;nt<2;nt++) acc[mt][nt] = (f32x4){0.f,0.f,0.f,0.f};

  auto pass = [&](const unsigned short* __restrict__ Ap, const unsigned short* __restrict__ Wp){
#pragma unroll
    for (int ks=0;ks<4;ks++){
      bfrag Af[4], Bf[2];
#pragma unroll
      for (int mt=0;mt<4;mt++)
        Af[mt] = *(const bfrag*)(Ap + (size_t)nodeM[mt]*128 + ks*32 + q*8);
#pragma unroll
      for (int nt=0;nt<2;nt++)
        Bf[nt] = *(const bfrag*)(Wp + (size_t)(j0 + nt*16 + ln)*128 + ks*32 + q*8);
#pragma unroll
      for (int mt=0;mt<4;mt++)
#pragma unroll
        for (int nt=0;nt<2;nt++)
          acc[mt][nt] = __builtin_amdgcn_mfma_f32_16x16x32_bf16(Af[mt], Bf[nt], acc[mt][nt], 0,0,0);
    }
  };
  pass(Ab, Wb);
  if (A2b) pass(A2b, W2b);

#pragma unroll
  for (int nt=0;nt<2;nt++){
    int j = j0 + nt*16 + ln;
    float bv = bias ? bias[j] : 0.f;
    if (bias2) bv += bias2[j];
#pragma unroll
    for (int mt=0;mt<4;mt++)
#pragma unroll
      for (int r=0;r<4;r++){
        int row = n0 + mt*16 + q*4 + r;
        if (row < n){
          float v = acc[mt][nt][r] + bv;
          if (dorelu) v = fmaxf(v, 0.f);
          if (outF) outF[(size_t)row*ostride + j] = v;
          if (outB) outB[(size_t)row*ostride + j] = f2bf(v);
        }
      }
  }
}

// MFMA LSTM v5: 512 thr (8 waves), 64 nodes/block, wave w owns 16 hidden cols x 4 gates.
// G[src] rows staged via global_load_lds (1 row = 1 wave-instr, 16B/lane), double-buffered
// in LDS. Pre-swizzled global source addr compensates the linear DMA so reads can use the
// XOR bank swizzle (m173 pattern). 148KB LDS -> 1 block/CU.
__global__ __launch_bounds__(512,2) void k_lstm5(
    const unsigned short* __restrict__ G,    // [n][512] bf16
    const int* __restrict__ src,             // [n*16]
    const unsigned short* __restrict__ Whhb, // [512][128] bf16
    unsigned short* __restrict__ aggb, int n)
{
  __shared__ unsigned short hs[64*128];        // 16 KB, row=node (256B), SWZ
  __shared__ unsigned short Gbuf[2][64*512];   // 2 x 64 KB, row=node (1024B), (row&7)<<4 XOR
  __shared__ int srcs[64*16];                  // 4 KB
  const int t  = threadIdx.x;
  const int w  = t >> 6;                       // 0..7
  const int l  = t & 63;
  const int ln = l & 15;
  const int q  = l >> 4;
  const int n0 = blockIdx.x * 64;

  for (int i = t; i < 1024; i += 512){
    int nl = i >> 4, st = i & 15;
    srcs[i] = (n0+nl < n) ? src[(size_t)(n0+nl)*16 + st] : 0;
  }

  // A-frags: lane ln provides A row m=ln -> gate T*128 + w*16 + ln
  bfrag A[4][4];
#pragma unroll
  for (int T=0;T<4;T++)
#pragma unroll
    for (int ks=0;ks<4;ks++)
      A[T][ks] = *(const bfrag*)(Whhb + (size_t)(T*128 + w*16 + ln)*128 + ks*32 + q*8);

  float c[4][4];
#pragma unroll
  for (int nt=0;nt<4;nt++)
#pragma unroll
    for (int r=0;r<4;r++) c[nt][r]=0.f;

  __syncthreads();   // srcs visible

  // DMA one step's 64 G rows: wave w loads rows [w*8, w*8+8)
  auto stageG = [&](int step, int buf){
#pragma unroll
    for (int j=0;j<8;j++){
      int row = w*8 + j;
      int sidx = srcs[row*16 + step];
      const char* gsrc = (const char*)G + (size_t)sidx*1024 + ((l*16) ^ ((row&7)<<4));
      char* ldst = (char*)&Gbuf[buf][0] + row*1024;
      GLDS16(gsrc, ldst);
    }
  };

  stageG(0, 0);
  asm volatile("s_waitcnt vmcnt(0)" ::: "memory");
  __syncthreads();   // Gbuf[0] ready

  for (int step=0; step<16; step++){
    const int cur = step & 1;
    if (step < 15) stageG(step+1, cur^1);

    f32x4 acc[4][4];  // [T][nt]
#pragma unroll
    for (int T=0;T<4;T++)
#pragma unroll
      for (int nt=0;nt<4;nt++) acc[T][nt] = (f32x4){0.f,0.f,0.f,0.f};

    if (step > 0){
#pragma unroll
      for (int np=0; np<2; np++){
        bfrag B[2][4];
#pragma unroll
        for (int ntl=0; ntl<2; ntl++){
          int node = (np*2+ntl)*16 + ln;
#pragma unroll
          for (int ks=0;ks<4;ks++)
            B[ntl][ks] = *(const bfrag*)((const char*)hs + node*256 +
                          (((ks*32+q*8)*2) ^ ((node&7)<<4)));
        }
#pragma unroll
        for (int T=0;T<4;T++)
#pragma unroll
          for (int ntl=0; ntl<2; ntl++)
#pragma unroll
            for (int ks=0;ks<4;ks++)
              acc[T][np*2+ntl] = __builtin_amdgcn_mfma_f32_16x16x32_bf16(
                  A[T][ks], B[ntl][ks], acc[T][np*2+ntl], 0, 0, 0);
      }
    }

    // gate inits from staged G rows (8B per gate, bank floor via XOR swizzle)
    uint2 gv[4][4];   // [nt][T]
#pragma unroll
    for (int nt=0;nt<4;nt++){
      int node = nt*16 + ln;
      const char* rowp = (const char*)&Gbuf[cur][0] + node*1024;
#pragma unroll
      for (int T=0;T<4;T++)
        gv[nt][T] = *(const uint2*)(rowp + ((T*256 + w*32 + q*8) ^ ((node&7)<<4)));
    }

    __syncthreads();   // hs reads + Gbuf[cur] reads done

#pragma unroll
    for (int nt=0;nt<4;nt++){
      int node = nt*16 + ln;
      unsigned int lo=0, hi=0;
#pragma unroll
      for (int r=0;r<4;r++){
        unsigned int gi = (r<2) ? (gv[nt][0].x >> (16*r)) : (gv[nt][0].y >> (16*(r-2)));
        unsigned int gf = (r<2) ? (gv[nt][1].x >> (16*r)) : (gv[nt][1].y >> (16*(r-2)));
        unsigned int gg = (r<2) ? (gv[nt][2].x >> (16*r)) : (gv[nt][2].y >> (16*(r-2)));
        unsigned int go = (r<2) ? (gv[nt][3].x >> (16*r)) : (gv[nt][3].y >> (16*(r-2)));
        float iv = acc[0][nt][r] + bf2f(gi & 0xffffu);
        float fv = acc[1][nt][r] + bf2f(gf & 0xffffu);
        float gvl= acc[2][nt][r] + bf2f(gg & 0xffffu);
        float ov = acc[3][nt][r] + bf2f(go & 0xffffu);
        float cn = sigmoidf_(fv)*c[nt][r] + sigmoidf_(iv)*tanh_fast(gvl);
        c[nt][r] = cn;
        float h = sigmoidf_(ov)*tanh_fast(cn);
        unsigned int hb = f2bf(h);
        if (r<2) lo |= hb << (16*r); else hi |= hb << (16*(r-2));
      }
      int kb = (w*16 + q*4)*2;
      uint2 pv; pv.x = lo; pv.y = hi;
      *(uint2*)((char*)hs + node*256 + (kb ^ ((node&7)<<4))) = pv;
      if (step == 15 && n0+node < n)
        *(uint2*)(aggb + (size_t)(n0+node)*128 + w*16 + q*4) = pv;
    }
    asm volatile("s_waitcnt vmcnt(0)" ::: "memory");  // DMA for step+1 landed
    __syncthreads();   // h + Gbuf[cur^1] visible for next step
  }
}

// Edge MLP, MFMA (unchanged).
__global__ __launch_bounds__(256,2) void k_edge2(
    const float* __restrict__ HsHd,
    const float* __restrict__ ea,
    const int* __restrict__ src,
    const unsigned short* __restrict__ W1eh, const unsigned short* __restrict__ W1el,
    const unsigned short* __restrict__ W2h,  const unsigned short* __restrict__ W2l,
    const unsigned short* __restrict__ W3p,
    const float* __restrict__ b1, const float* __restrict__ b2, const float* __restrict__ b3,
    float* __restrict__ out)
{
  __shared__ unsigned short out1h[64*128];
  __shared__ unsigned short out1l[64*128];
  __shared__ unsigned short e2h[64*64];
  __shared__ unsigned short e2l[64*64];
  __shared__ unsigned short ea2[64*56];
  __shared__ float hd[4*128];
  __shared__ int srcs[64];

  const int t = threadIdx.x;
  const int w = t>>6, l = t&63, ln = l&15, q = l>>4;
  const int nblk = blockIdx.x;
  const size_t e0 = (size_t)nblk*64;

  for (int i=t;i<1024;i+=256){
    int e=i>>4, k=i&15;
    float v = ea[(e0+e)*16 + k];
    unsigned short hi = f2bf(v);
    ea2[e*56 + k] = hi;
    ea2[e*56 + 16 + k] = f2bf(v - bf2f(hi));
  }
  for (int i=t;i<512;i+=256){
    int d=i>>7, j=i&127;
    hd[d*128+j] = HsHd[((size_t)nblk*4+d)*256 + 128 + j];
  }
  if (t<64) srcs[t] = src[e0+t];
  __syncthreads();

  {
    bfrag Aea = *(const bfrag*)&ea2[(w*16+ln)*56 + q*8];
#pragma unroll
    for (int nt=0;nt<8;nt++){
      int j = nt*16 + ln;
      bfrag B1 = *(const bfrag*)(W1eh + (size_t)j*16 + (q&1)*8);
      bfrag B2 = *(const bfrag*)(W1el + (size_t)j*16 + (q&1)*8);
      float b1v = b1[j];
      float hdv = hd[w*128 + j];
      f32x4 acc;
#pragma unroll
      for (int r=0;r<4;r++){
        int edge = w*16 + q*4 + r;
        acc[r] = b1v + hdv + HsHd[(size_t)srcs[edge]*256 + j];
      }
      acc = __builtin_amdgcn_mfma_f32_16x16x32_bf16(Aea, B1, acc, 0,0,0);
      acc = __builtin_amdgcn_mfma_f32_16x16x32_bf16(Aea, B2, acc, 0,0,0);
#pragma unroll
      for (int r=0;r<4;r++){
        int row = w*16 + q*4 + r;
        float v = fmaxf(acc[r], 0.f);
        unsigned short hi = f2bf(v);
        float lo = v - bf2f(hi);
        int byt = row*256 + ((j*2) ^ SWZ(row));
        *(unsigned short*)((char*)out1h + byt) = hi;
        *(unsigned short*)((char*)out1l + byt) = f2bf(lo);
      }
    }
  }
  __syncthreads();

  {
    f32x4 acc[4];
#pragma unroll
    for (int nt=0;nt<4;nt++){ float bv = b2[nt*16+ln]; acc[nt] = (f32x4){bv,bv,bv,bv}; }
    int arow = w*16 + ln;
#pragma unroll
    for (int ks=0;ks<4;ks++){
      int byt = arow*256 + ((ks*64 + q*16) ^ SWZ(arow));
      bfrag Ah = *(const bfrag*)((char*)out1h + byt);
      bfrag Al = *(const bfrag*)((char*)out1l + byt);
#pragma unroll
      for (int nt=0;nt<4;nt++){
        int j = nt*16 + ln;
        bfrag Bh = *(const bfrag*)(W2h + (size_t)j*128 + ks*32 + q*8);
        bfrag Bl = *(const bfrag*)(W2l + (size_t)j*128 + ks*32 + q*8);
        acc[nt] = __builtin_amdgcn_mfma_f32_16x16x32_bf16(Ah, Bh, acc[nt], 0,0,0);
        acc[nt] = __builtin_amdgcn_mfma_f32_16x16x32_bf16(Al, Bh, acc[nt], 0,0,0);
        acc[nt] = __builtin_amdgcn_mfma_f32_16x16x32_bf16(Ah, Bl, acc[nt], 0,0,0);
      }
    }
#pragma unroll
    for (int nt=0;nt<4;nt++)
#pragma unroll
      for (int r=0;r<4;r++){
        int row = w*16 + q*4 + r;
        int j = nt*16 + ln;
        float v = fmaxf(acc[nt][r], 0.f);
        unsigned short hi = f2bf(v);
        float lo = v - bf2f(hi);
        int byt = row*128 + ((j*2) ^ SWZ(row));
        *(unsigned short*)((char*)e2h + byt) = hi;
        *(unsigned short*)((char*)e2l + byt) = f2bf(lo);
      }
  }
  __syncthreads();

  {
    float b3v = (ln<2) ? b3[ln] : 0.f;
    f32x4 acc = (f32x4){b3v,b3v,b3v,b3v};
    int arow = w*16 + ln;
#pragma unroll
    for (int ks=0;ks<2;ks++){
      int byt = arow*128 + ((ks*64 + q*16) ^ SWZ(arow));
      bfrag Ah = *(const bfrag*)((char*)e2h + byt);
      bfrag Al = *(const bfrag*)((char*)e2l + byt);
      bfrag B  = *(const bfrag*)(W3p + (size_t)ln*64 + ks*32 + q*8);
      acc = __builtin_amdgcn_mfma_f32_16x16x32_bf16(Ah, B, acc, 0,0,0);
      acc = __builtin_amdgcn_mfma_f32_16x16x32_bf16(Al, B, acc, 0,0,0);
    }
    if (ln < 2){
#pragma unroll
      for (int r=0;r<4;r++){
        int row = w*16 + q*4 + r;
        out[(e0 + row)*2 + ln] = acc[r];
      }
    }
  }
}

extern "C" void kernel_launch(void* const* d_in, const int* in_sizes, int n_in,
                              void* d_out, int out_size, void* d_ws, size_t ws_size,
                              hipStream_t stream) {
  const float* x    = (const float*)d_in[0];
  const int*   eidx = (const int*)  d_in[1];
  const float* eatt = (const float*)d_in[2];
  const float* Wih  = (const float*)d_in[3];
  const float* Whh  = (const float*)d_in[4];
  const float* bih  = (const float*)d_in[5];
  const float* bhh  = (const float*)d_in[6];
  const float* WlL  = (const float*)d_in[7];
  const float* blL  = (const float*)d_in[8];
  const float* WrL  = (const float*)d_in[9];
  const float* W1   = (const float*)d_in[10];
  const float* b1   = (const float*)d_in[11];
  const float* W2   = (const float*)d_in[12];
  const float* b2   = (const float*)d_in[13];
  const float* W3   = (const float*)d_in[14];
  const float* b3   = (const float*)d_in[15];
  const int*   src  = eidx;

  char* p = (char*)d_ws;
  unsigned short* Gb = (unsigned short*)p;      // [NN][512] bf16
  float* HsHd        = (float*)p;               // [NN][256] f32 (aliases Gb; Gb dead by then)
  p += (size_t)NN*512*2;
  unsigned short* xb   = (unsigned short*)p; p += (size_t)NN*128*2;
  unsigned short* hb1  = (unsigned short*)p; p += (size_t)NN*128*2;
  unsigned short* hb2  = (unsigned short*)p; p += (size_t)NN*128*2;
  unsigned short* aggb = (unsigned short*)p; p += (size_t)NN*128*2;
  unsigned short* Wihb = (unsigned short*)p; p += (size_t)3*512*128*2;
  unsigned short* Whhb = (unsigned short*)p; p += (size_t)3*512*128*2;
  unsigned short* Wlb  = (unsigned short*)p; p += (size_t)3*128*128*2;
  unsigned short* Wrb  = (unsigned short*)p; p += (size_t)3*128*128*2;
  unsigned short* W1nb = (unsigned short*)p; p += (size_t)256*128*2;
  unsigned short* W1eh = (unsigned short*)p; p += 2048*2;
  unsigned short* W1el = (unsigned short*)p; p += 2048*2;
  unsigned short* W2h  = (unsigned short*)p; p += 8192*2;
  unsigned short* W2l  = (unsigned short*)p; p += 8192*2;
  unsigned short* W3p  = (unsigned short*)p; p += 1024*2;

  dim3 blk(256);
  const int nb = (NN + 63)/64;

  k_cvt<<<(NN*128+255)/256, blk, 0, stream>>>(x, xb, NN*128);
  k_cvt<<<(3*512*128+255)/256, blk, 0, stream>>>(Wih, Wihb, 3*512*128);
  k_cvt<<<(3*512*128+255)/256, blk, 0, stream>>>(Whh, Whhb, 3*512*128);
  k_cvt<<<(3*128*128+255)/256, blk, 0, stream>>>(WlL, Wlb, 3*128*128);
  k_cvt<<<(3*128*128+255)/256, blk, 0, stream>>>(WrL, Wrb, 3*128*128);
  k_cvt2<<<(128*128+255)/256, blk, 0, stream>>>(W1, W1nb,           272, 0,   128, 128*128);
  k_cvt2<<<(128*128+255)/256, blk, 0, stream>>>(W1, W1nb+128*128,   272, 128, 128, 128*128);
  k_prep_edge<<<(11264+255)/256, blk, 0, stream>>>(W1, W2, W3, W1eh, W1el, W2h, W2l, W3p);

  const unsigned short* hin = xb;
  unsigned short* houts[3] = {hb1, hb2, hb1};
  for (int l = 0; l < 3; l++){
    k_bgemm<<<dim3(nb,4),blk,0,stream>>>(hin, nullptr,
        Wihb + (size_t)l*512*128, nullptr,
        bih + (size_t)l*512, bhh + (size_t)l*512,
        nullptr, Gb, 512, 0, NN);
    k_lstm5<<<dim3(nb),dim3(512),0,stream>>>(Gb, src, Whhb + (size_t)l*512*128, aggb, NN);
    k_bgemm<<<dim3(nb,1),blk,0,stream>>>(aggb, hin,
        Wlb + (size_t)l*128*128, Wrb + (size_t)l*128*128,
        blL + (size_t)l*128, nullptr,
        nullptr, houts[l], 128, 1, NN);
    hin = houts[l];
  }
  k_bgemm<<<dim3(nb,2),blk,0,stream>>>(hin, nullptr, W1nb, nullptr,
                                       nullptr, nullptr, HsHd, nullptr, 256, 0, NN);
  k_edge2<<<dim3(NN/4),blk,0,stream>>>(HsHd, eatt, src, W1eh, W1el, W2h, W2l, W3p,
                                       b1, b2, b3, (float*)d_out);
}

// Round 6
// 1497.514 us; speedup vs baseline: 6.2009x; 1.0179x over previous
//
#include <hip/hip_runtime.h>
#include <hip/hip_bf16.h>

#define NN 50000
#define DEG 16

typedef __attribute__((ext_vector_type(8))) short bfrag;   // 8 x bf16 bits (16B)
typedef __attribute__((ext_vector_type(4))) float f32x4;

__device__ __forceinline__ float bf2f(unsigned int u){ return __uint_as_float(u<<16); }
__device__ __forceinline__ unsigned short f2bf(float x){
  unsigned int u = __float_as_uint(x);
  unsigned int r = (u + 0x7fffu + ((u>>16)&1u)) >> 16;
  return (unsigned short)r;
}
__device__ __forceinline__ float fast_rcp(float x){ return __builtin_amdgcn_rcpf(x); }
__device__ __forceinline__ float sigmoidf_(float x){ return fast_rcp(1.f + __expf(-x)); }
__device__ __forceinline__ float tanh_fast(float x){
  float e = __expf(-2.f*fabsf(x));
  float r = (1.f - e)*fast_rcp(1.f + e);
  return copysignf(r, x);
}

#define SWZ(row) (((((row) ^ ((row)>>3)) & 7)) << 4)

// global->LDS DMA, 16B per lane; LDS dest is wave-uniform base + lane*16 (linear).
#define GLDS16(g, l) __builtin_amdgcn_global_load_lds( \
    (const __attribute__((address_space(1))) unsigned int*)(g), \
    (__attribute__((address_space(3))) unsigned int*)(l), 16, 0, 0)

__global__ void k_cvt(const float* __restrict__ in, unsigned short* __restrict__ out, int n){
  int i = blockIdx.x*256 + threadIdx.x;
  if (i < n) out[i] = f2bf(in[i]);
}

__global__ void k_cvt2(const float* __restrict__ in, unsigned short* __restrict__ out,
                       int stride, int off, int cols, int total){
  int i = blockIdx.x*256 + threadIdx.x;
  if (i < total){
    int r = i / cols, c = i - r*cols;
    out[i] = f2bf(in[(size_t)r*stride + off + c]);
  }
}

__global__ void k_prep_edge(const float* __restrict__ W1, const float* __restrict__ W2,
                            const float* __restrict__ W3,
                            unsigned short* __restrict__ W1eh, unsigned short* __restrict__ W1el,
                            unsigned short* __restrict__ W2h, unsigned short* __restrict__ W2l,
                            unsigned short* __restrict__ W3p)
{
  int i = blockIdx.x*256 + threadIdx.x;
  if (i < 8192){
    float v = W2[i];
    unsigned short hi = f2bf(v);
    W2h[i] = hi; W2l[i] = f2bf(v - bf2f(hi));
  } else if (i < 10240){
    int k = i - 8192; int j = k >> 4, kk = k & 15;
    float v = W1[(size_t)j*272 + 256 + kk];
    unsigned short hi = f2bf(v);
    W1eh[k] = hi; W1el[k] = f2bf(v - bf2f(hi));
  } else if (i < 11264){
    int k = i - 10240; int nr = k >> 6, c = k & 63;
    W3p[k] = f2bf(nr < 2 ? W3[nr*64 + c] : 0.f);
  }
}

// bf16 MFMA gemm (unchanged).
__global__ __launch_bounds__(256,4) void k_bgemm(
    const unsigned short* __restrict__ Ab, const unsigned short* __restrict__ A2b,
    const unsigned short* __restrict__ Wb, const unsigned short* __restrict__ W2b,
    const float* __restrict__ bias, const float* __restrict__ bias2,
    float* __restrict__ outF, unsigned short* __restrict__ outB,
    int ostride, int dorelu, int n)
{
  const int t  = threadIdx.x;
  const int w  = t >> 6;
  const int l  = t & 63;
  const int ln = l & 15, q = l >> 4;
  const int n0 = blockIdx.x*64;
  const int j0 = blockIdx.y*128 + w*32;

  int nodeM[4];
#pragma unroll
  for (int mt=0;mt<4;mt++){ int nd = n0 + mt*16 + ln; nodeM[mt] = nd < n ? nd : n-1; }

  f32x4 acc[4][2];
#pragma unroll
  for (int mt=0;mt<4;mt++)
#pragma unroll
    for (int nt=0;nt<2;nt++) acc[mt][nt] = (f32x4){0.f,0.f,0.f,0.f};

  auto pass = [&](const unsigned short* __restrict__ Ap, const unsigned short* __restrict__ Wp){
#pragma unroll
    for (int ks=0;ks<4;ks++){
      bfrag Af[4], Bf[2];
#pragma unroll
      for (int mt=0;mt<4;mt++)
        Af[mt] = *(const bfrag*)(Ap + (size_t)nodeM[mt]*128 + ks*32 + q*8);
#pragma unroll
      for (int nt=0;nt<2;nt++)
        Bf[nt] = *(const bfrag*)(Wp + (size_t)(j0 + nt*16 + ln)*128 + ks*32 + q*8);
#pragma unroll
      for (int mt=0;mt<4;mt++)
#pragma unroll
        for (int nt=0;nt<2;nt++)
          acc[mt][nt] = __builtin_amdgcn_mfma_f32_16x16x32_bf16(Af[mt], Bf[nt], acc[mt][nt], 0,0,0);
    }
  };
  pass(Ab, Wb);
  if (A2b) pass(A2b, W2b);

#pragma unroll
  for (int nt=0;nt<2;nt++){
    int j = j0 + nt*16 + ln;
    float bv = bias ? bias[j] : 0.f;
    if (bias2) bv += bias2[j];
#pragma unroll
    for (int mt=0;mt<4;mt++)
#pragma unroll
      for (int r=0;r<4;r++){
        int row = n0 + mt*16 + q*4 + r;
        if (row < n){
          float v = acc[mt][nt][r] + bv;
          if (dorelu) v = fmaxf(v, 0.f);
          if (outF) outF[(size_t)row*ostride + j] = v;
          if (outB) outB[(size_t)row*ostride + j] = f2bf(v);
        }
      }
  }
}

// MFMA LSTM v5 (unchanged from R5).
__global__ __launch_bounds__(512,2) void k_lstm5(
    const unsigned short* __restrict__ G,
    const int* __restrict__ src,
    const unsigned short* __restrict__ Whhb,
    unsigned short* __restrict__ aggb, int n)
{
  __shared__ unsigned short hs[64*128];
  __shared__ unsigned short Gbuf[2][64*512];
  __shared__ int srcs[64*16];
  const int t  = threadIdx.x;
  const int w  = t >> 6;
  const int l  = t & 63;
  const int ln = l & 15;
  const int q  = l >> 4;
  const int n0 = blockIdx.x * 64;

  for (int i = t; i < 1024; i += 512){
    int nl = i >> 4, st = i & 15;
    srcs[i] = (n0+nl < n) ? src[(size_t)(n0+nl)*16 + st] : 0;
  }

  bfrag A[4][4];
#pragma unroll
  for (int T=0;T<4;T++)
#pragma unroll
    for (int ks=0;ks<4;ks++)
      A[T][ks] = *(const bfrag*)(Whhb + (size_t)(T*128 + w*16 + ln)*128 + ks*32 + q*8);

  float c[4][4];
#pragma unroll
  for (int nt=0;nt<4;nt++)
#pragma unroll
    for (int r=0;r<4;r++) c[nt][r]=0.f;

  __syncthreads();

  auto stageG = [&](int step, int buf){
#pragma unroll
    for (int j=0;j<8;j++){
      int row = w*8 + j;
      int sidx = srcs[row*16 + step];
      const char* gsrc = (const char*)G + (size_t)sidx*1024 + ((l*16) ^ ((row&7)<<4));
      char* ldst = (char*)&Gbuf[buf][0] + row*1024;
      GLDS16(gsrc, ldst);
    }
  };

  stageG(0, 0);
  asm volatile("s_waitcnt vmcnt(0)" ::: "memory");
  __syncthreads();

  for (int step=0; step<16; step++){
    const int cur = step & 1;
    if (step < 15) stageG(step+1, cur^1);

    f32x4 acc[4][4];
#pragma unroll
    for (int T=0;T<4;T++)
#pragma unroll
      for (int nt=0;nt<4;nt++) acc[T][nt] = (f32x4){0.f,0.f,0.f,0.f};

    if (step > 0){
#pragma unroll
      for (int np=0; np<2; np++){
        bfrag B[2][4];
#pragma unroll
        for (int ntl=0; ntl<2; ntl++){
          int node = (np*2+ntl)*16 + ln;
#pragma unroll
          for (int ks=0;ks<4;ks++)
            B[ntl][ks] = *(const bfrag*)((const char*)hs + node*256 +
                          (((ks*32+q*8)*2) ^ ((node&7)<<4)));
        }
#pragma unroll
        for (int T=0;T<4;T++)
#pragma unroll
          for (int ntl=0; ntl<2; ntl++)
#pragma unroll
            for (int ks=0;ks<4;ks++)
              acc[T][np*2+ntl] = __builtin_amdgcn_mfma_f32_16x16x32_bf16(
                  A[T][ks], B[ntl][ks], acc[T][np*2+ntl], 0, 0, 0);
      }
    }

    uint2 gv[4][4];
#pragma unroll
    for (int nt=0;nt<4;nt++){
      int node = nt*16 + ln;
      const char* rowp = (const char*)&Gbuf[cur][0] + node*1024;
#pragma unroll
      for (int T=0;T<4;T++)
        gv[nt][T] = *(const uint2*)(rowp + ((T*256 + w*32 + q*8) ^ ((node&7)<<4)));
    }

    __syncthreads();

#pragma unroll
    for (int nt=0;nt<4;nt++){
      int node = nt*16 + ln;
      unsigned int lo=0, hi=0;
#pragma unroll
      for (int r=0;r<4;r++){
        unsigned int gi = (r<2) ? (gv[nt][0].x >> (16*r)) : (gv[nt][0].y >> (16*(r-2)));
        unsigned int gf = (r<2) ? (gv[nt][1].x >> (16*r)) : (gv[nt][1].y >> (16*(r-2)));
        unsigned int gg = (r<2) ? (gv[nt][2].x >> (16*r)) : (gv[nt][2].y >> (16*(r-2)));
        unsigned int go = (r<2) ? (gv[nt][3].x >> (16*r)) : (gv[nt][3].y >> (16*(r-2)));
        float iv = acc[0][nt][r] + bf2f(gi & 0xffffu);
        float fv = acc[1][nt][r] + bf2f(gf & 0xffffu);
        float gvl= acc[2][nt][r] + bf2f(gg & 0xffffu);
        float ov = acc[3][nt][r] + bf2f(go & 0xffffu);
        float cn = sigmoidf_(fv)*c[nt][r] + sigmoidf_(iv)*tanh_fast(gvl);
        c[nt][r] = cn;
        float h = sigmoidf_(ov)*tanh_fast(cn);
        unsigned int hb = f2bf(h);
        if (r<2) lo |= hb << (16*r); else hi |= hb << (16*(r-2));
      }
      int kb = (w*16 + q*4)*2;
      uint2 pv; pv.x = lo; pv.y = hi;
      *(uint2*)((char*)hs + node*256 + (kb ^ ((node&7)<<4))) = pv;
      if (step == 15 && n0+node < n)
        *(uint2*)(aggb + (size_t)(n0+node)*128 + w*16 + q*4) = pv;
    }
    asm volatile("s_waitcnt vmcnt(0)" ::: "memory");
    __syncthreads();
  }
}

// Edge MLP v3: 4 dst (64 edges)/block. All scattered/global operands preloaded
// to regs in one batch at the top (issue-early); phase-2 W2 frags reg-double-buffered.
__global__ __launch_bounds__(256,2) void k_edge3(
    const float* __restrict__ HsHd,   // [N][256] f32: 0..127 Hs, 128..255 Hd
    const float* __restrict__ ea,     // [E][16]
    const int* __restrict__ src,
    const unsigned short* __restrict__ W1eh, const unsigned short* __restrict__ W1el, // [128][16]
    const unsigned short* __restrict__ W2h,  const unsigned short* __restrict__ W2l,  // [64][128]
    const unsigned short* __restrict__ W3p,  // [16][64]
    const float* __restrict__ b1, const float* __restrict__ b2, const float* __restrict__ b3,
    float* __restrict__ out)
{
  __shared__ unsigned short out1h[64*128];  // 16 KB, row stride 256B, SWZ
  __shared__ unsigned short out1l[64*128];  // 16 KB
  __shared__ unsigned short e2h[64*64];     // 8 KB, row stride 128B, SWZ
  __shared__ unsigned short e2l[64*64];     // 8 KB
  __shared__ unsigned short ea2[64*56];     // 7 KB

  const int t = threadIdx.x;
  const int w = t>>6, l = t&63, ln = l&15, q = l>>4;
  const int nblk = blockIdx.x;
  const size_t e0 = (size_t)nblk*64;

  // ---- batch preload: everything scattered/global -> regs, issued together ----
  int srcv[4];
#pragma unroll
  for (int r=0;r<4;r++) srcv[r] = src[e0 + w*16 + q*4 + r];

  float hsv[8][4];     // Hs[src[edge(r)]][nt*16+ln]
#pragma unroll
  for (int nt=0;nt<8;nt++)
#pragma unroll
    for (int r=0;r<4;r++)
      hsv[nt][r] = HsHd[(size_t)srcv[r]*256 + nt*16 + ln];

  float hdv[8];        // Hd[dst=w][nt*16+ln]
#pragma unroll
  for (int nt=0;nt<8;nt++)
    hdv[nt] = HsHd[((size_t)nblk*4 + w)*256 + 128 + nt*16 + ln];

  float b1v[8];
#pragma unroll
  for (int nt=0;nt<8;nt++) b1v[nt] = b1[nt*16 + ln];
  float b2v[4];
#pragma unroll
  for (int nt=0;nt<4;nt++) b2v[nt] = b2[nt*16 + ln];
  float b3v = (ln<2) ? b3[ln] : 0.f;

  bfrag w1h[8], w1l[8];   // W1e B-frags (hi dup / lo dup across K halves)
#pragma unroll
  for (int nt=0;nt<8;nt++){
    int j = nt*16 + ln;
    w1h[nt] = *(const bfrag*)(W1eh + (size_t)j*16 + (q&1)*8);
    w1l[nt] = *(const bfrag*)(W1el + (size_t)j*16 + (q&1)*8);
  }
  bfrag w3f[2];
#pragma unroll
  for (int ks=0;ks<2;ks++)
    w3f[ks] = *(const bfrag*)(W3p + (size_t)ln*64 + ks*32 + q*8);

  // ---- LDS staging (cross-wave): ea hi/lo transpose-ish ----
  for (int i=t;i<1024;i+=256){
    int e=i>>4, k=i&15;
    float v = ea[(e0+e)*16 + k];
    unsigned short hi = f2bf(v);
    ea2[e*56 + k] = hi;
    ea2[e*56 + 16 + k] = f2bf(v - bf2f(hi));
  }
  __syncthreads();

  // ---- phase 1: out1 = relu(Hs+Hd+b1 + ea@W1e^T) -> hi/lo LDS ----
  {
    bfrag Aea = *(const bfrag*)&ea2[(w*16+ln)*56 + q*8];
#pragma unroll
    for (int nt=0;nt<8;nt++){
      f32x4 acc;
#pragma unroll
      for (int r=0;r<4;r++) acc[r] = b1v[nt] + hdv[nt] + hsv[nt][r];
      acc = __builtin_amdgcn_mfma_f32_16x16x32_bf16(Aea, w1h[nt], acc, 0,0,0);
      acc = __builtin_amdgcn_mfma_f32_16x16x32_bf16(Aea, w1l[nt], acc, 0,0,0);
      int j = nt*16 + ln;
#pragma unroll
      for (int r=0;r<4;r++){
        int row = w*16 + q*4 + r;
        float v = fmaxf(acc[r], 0.f);
        unsigned short hi = f2bf(v);
        float lo = v - bf2f(hi);
        int byt = row*256 + ((j*2) ^ SWZ(row));
        *(unsigned short*)((char*)out1h + byt) = hi;
        *(unsigned short*)((char*)out1l + byt) = f2bf(lo);
      }
    }
  }
  __syncthreads();

  // ---- phase 2: e2 = relu(out1@W2^T + b2); W2 frags reg-double-buffered ----
  {
    f32x4 acc[4];
#pragma unroll
    for (int nt=0;nt<4;nt++) acc[nt] = (f32x4){b2v[nt],b2v[nt],b2v[nt],b2v[nt]};
    int arow = w*16 + ln;

    bfrag BhA[4], BlA[4], BhB[4], BlB[4];
#pragma unroll
    for (int nt=0;nt<4;nt++){
      int j = nt*16 + ln;
      BhA[nt] = *(const bfrag*)(W2h + (size_t)j*128 + q*8);
      BlA[nt] = *(const bfrag*)(W2l + (size_t)j*128 + q*8);
    }
#pragma unroll
    for (int ks=0;ks<4;ks++){
      // prefetch next ks
      if (ks < 3){
#pragma unroll
        for (int nt=0;nt<4;nt++){
          int j = nt*16 + ln;
          if ((ks&1)==0){
            BhB[nt] = *(const bfrag*)(W2h + (size_t)j*128 + (ks+1)*32 + q*8);
            BlB[nt] = *(const bfrag*)(W2l + (size_t)j*128 + (ks+1)*32 + q*8);
          } else {
            BhA[nt] = *(const bfrag*)(W2h + (size_t)j*128 + (ks+1)*32 + q*8);
            BlA[nt] = *(const bfrag*)(W2l + (size_t)j*128 + (ks+1)*32 + q*8);
          }
        }
      }
      int byt = arow*256 + ((ks*64 + q*16) ^ SWZ(arow));
      bfrag Ah = *(const bfrag*)((char*)out1h + byt);
      bfrag Al = *(const bfrag*)((char*)out1l + byt);
#pragma unroll
      for (int nt=0;nt<4;nt++){
        bfrag Bh = ((ks&1)==0) ? BhA[nt] : BhB[nt];
        bfrag Bl = ((ks&1)==0) ? BlA[nt] : BlB[nt];
        acc[nt] = __builtin_amdgcn_mfma_f32_16x16x32_bf16(Ah, Bh, acc[nt], 0,0,0);
        acc[nt] = __builtin_amdgcn_mfma_f32_16x16x32_bf16(Al, Bh, acc[nt], 0,0,0);
        acc[nt] = __builtin_amdgcn_mfma_f32_16x16x32_bf16(Ah, Bl, acc[nt], 0,0,0);
      }
    }
#pragma unroll
    for (int nt=0;nt<4;nt++)
#pragma unroll
      for (int r=0;r<4;r++){
        int row = w*16 + q*4 + r;
        int j = nt*16 + ln;
        float v = fmaxf(acc[nt][r], 0.f);
        unsigned short hi = f2bf(v);
        float lo = v - bf2f(hi);
        int byt = row*128 + ((j*2) ^ SWZ(row));
        *(unsigned short*)((char*)e2h + byt) = hi;
        *(unsigned short*)((char*)e2l + byt) = f2bf(lo);
      }
  }
  __syncthreads();

  // ---- phase 3: out = e2@W3^T + b3 ----
  {
    f32x4 acc = (f32x4){b3v,b3v,b3v,b3v};
    int arow = w*16 + ln;
#pragma unroll
    for (int ks=0;ks<2;ks++){
      int byt = arow*128 + ((ks*64 + q*16) ^ SWZ(arow));
      bfrag Ah = *(const bfrag*)((char*)e2h + byt);
      bfrag Al = *(const bfrag*)((char*)e2l + byt);
      acc = __builtin_amdgcn_mfma_f32_16x16x32_bf16(Ah, w3f[ks], acc, 0,0,0);
      acc = __builtin_amdgcn_mfma_f32_16x16x32_bf16(Al, w3f[ks], acc, 0,0,0);
    }
    if (ln < 2){
#pragma unroll
      for (int r=0;r<4;r++){
        int row = w*16 + q*4 + r;
        out[(e0 + row)*2 + ln] = acc[r];
      }
    }
  }
}

extern "C" void kernel_launch(void* const* d_in, const int* in_sizes, int n_in,
                              void* d_out, int out_size, void* d_ws, size_t ws_size,
                              hipStream_t stream) {
  const float* x    = (const float*)d_in[0];
  const int*   eidx = (const int*)  d_in[1];
  const float* eatt = (const float*)d_in[2];
  const float* Wih  = (const float*)d_in[3];
  const float* Whh  = (const float*)d_in[4];
  const float* bih  = (const float*)d_in[5];
  const float* bhh  = (const float*)d_in[6];
  const float* WlL  = (const float*)d_in[7];
  const float* blL  = (const float*)d_in[8];
  const float* WrL  = (const float*)d_in[9];
  const float* W1   = (const float*)d_in[10];
  const float* b1   = (const float*)d_in[11];
  const float* W2   = (const float*)d_in[12];
  const float* b2   = (const float*)d_in[13];
  const float* W3   = (const float*)d_in[14];
  const float* b3   = (const float*)d_in[15];
  const int*   src  = eidx;

  char* p = (char*)d_ws;
  unsigned short* Gb = (unsigned short*)p;      // [NN][512] bf16
  float* HsHd        = (float*)p;               // [NN][256] f32 (aliases Gb; Gb dead by then)
  p += (size_t)NN*512*2;
  unsigned short* xb   = (unsigned short*)p; p += (size_t)NN*128*2;
  unsigned short* hb1  = (unsigned short*)p; p += (size_t)NN*128*2;
  unsigned short* hb2  = (unsigned short*)p; p += (size_t)NN*128*2;
  unsigned short* aggb = (unsigned short*)p; p += (size_t)NN*128*2;
  unsigned short* Wihb = (unsigned short*)p; p += (size_t)3*512*128*2;
  unsigned short* Whhb = (unsigned short*)p; p += (size_t)3*512*128*2;
  unsigned short* Wlb  = (unsigned short*)p; p += (size_t)3*128*128*2;
  unsigned short* Wrb  = (unsigned short*)p; p += (size_t)3*128*128*2;
  unsigned short* W1nb = (unsigned short*)p; p += (size_t)256*128*2;
  unsigned short* W1eh = (unsigned short*)p; p += 2048*2;
  unsigned short* W1el = (unsigned short*)p; p += 2048*2;
  unsigned short* W2h  = (unsigned short*)p; p += 8192*2;
  unsigned short* W2l  = (unsigned short*)p; p += 8192*2;
  unsigned short* W3p  = (unsigned short*)p; p += 1024*2;

  dim3 blk(256);
  const int nb = (NN + 63)/64;

  k_cvt<<<(NN*128+255)/256, blk, 0, stream>>>(x, xb, NN*128);
  k_cvt<<<(3*512*128+255)/256, blk, 0, stream>>>(Wih, Wihb, 3*512*128);
  k_cvt<<<(3*512*128+255)/256, blk, 0, stream>>>(Whh, Whhb, 3*512*128);
  k_cvt<<<(3*128*128+255)/256, blk, 0, stream>>>(WlL, Wlb, 3*128*128);
  k_cvt<<<(3*128*128+255)/256, blk, 0, stream>>>(WrL, Wrb, 3*128*128);
  k_cvt2<<<(128*128+255)/256, blk, 0, stream>>>(W1, W1nb,           272, 0,   128, 128*128);
  k_cvt2<<<(128*128+255)/256, blk, 0, stream>>>(W1, W1nb+128*128,   272, 128, 128, 128*128);
  k_prep_edge<<<(11264+255)/256, blk, 0, stream>>>(W1, W2, W3, W1eh, W1el, W2h, W2l, W3p);

  const unsigned short* hin = xb;
  unsigned short* houts[3] = {hb1, hb2, hb1};
  for (int l = 0; l < 3; l++){
    k_bgemm<<<dim3(nb,4),blk,0,stream>>>(hin, nullptr,
        Wihb + (size_t)l*512*128, nullptr,
        bih + (size_t)l*512, bhh + (size_t)l*512,
        nullptr, Gb, 512, 0, NN);
    k_lstm5<<<dim3(nb),dim3(512),0,stream>>>(Gb, src, Whhb + (size_t)l*512*128, aggb, NN);
    k_bgemm<<<dim3(nb,1),blk,0,stream>>>(aggb, hin,
        Wlb + (size_t)l*128*128, Wrb + (size_t)l*128*128,
        blL + (size_t)l*128, nullptr,
        nullptr, houts[l], 128, 1, NN);
    hin = houts[l];
  }
  k_bgemm<<<dim3(nb,2),blk,0,stream>>>(hin, nullptr, W1nb, nullptr,
                                       nullptr, nullptr, HsHd, nullptr, 256, 0, NN);
  k_edge3<<<dim3(NN/4),blk,0,stream>>>(HsHd, eatt, src, W1eh, W1el, W2h, W2l, W3p,
                                       b1, b2, b3, (float*)d_out);
}